// Round 1
// baseline (676.839 us; speedup 1.0000x reference)
//
#include <hip/hip_runtime.h>
#include <stdint.h>

typedef unsigned short u16;
typedef __attribute__((ext_vector_type(8))) short bf16x8;
typedef __attribute__((ext_vector_type(4))) short bf16x4;
typedef __attribute__((ext_vector_type(4))) float f32x4;

constexpr int DMODEL = 1536;
constexpr int SEQ    = 3072;
constexpr int NHEAD  = 12;
constexpr int HDIM   = 128;

__device__ __forceinline__ u16 f2bf(float f){
  union { float f; unsigned u; } v; v.f = f;
  return (u16)((v.u + 0x7fffu + ((v.u >> 16) & 1u)) >> 16);
}

// ---------------- convert f32 -> bf16 ----------------
__global__ __launch_bounds__(256) void cvt4_kernel(const float* __restrict__ src,
                                                   u16* __restrict__ dst, int n4){
  int i = blockIdx.x * 256 + threadIdx.x;
  if (i < n4){
    float4 f = ((const float4*)src)[i];
    ushort4 o;
    o.x = f2bf(f.x); o.y = f2bf(f.y); o.z = f2bf(f.z); o.w = f2bf(f.w);
    ((ushort4*)dst)[i] = o;
  }
}

// ---------------- GEMM core: C[128x128] = A[128xK] * W[128xK]^T + bias ----------------
__device__ __forceinline__ void gload16(const u16* g, u16* l){
  __builtin_amdgcn_global_load_lds((const __attribute__((address_space(1))) void*)g,
                                   (__attribute__((address_space(3))) void*)l, 16, 0, 0);
}

__device__ __forceinline__ void gemm_core(const u16* __restrict__ A, const u16* __restrict__ W,
    const float* __restrict__ bias, float* __restrict__ C, int m0, int n0,
    u16* As, u16* Bs)
{
  const int tid  = threadIdx.x;
  const int lane = tid & 63;
  const int wv   = tid >> 6;          // 0..3
  const int wm   = wv & 1, wn = wv >> 1;
  const int l15  = lane & 15, lg = lane >> 4;

  f32x4 acc[4][4];
#pragma unroll
  for (int i = 0; i < 4; i++)
#pragma unroll
    for (int j = 0; j < 4; j++){ f32x4 z = {0.f,0.f,0.f,0.f}; acc[i][j] = z; }

  const int r0 = wv * 16 + (lane >> 2);        // rows for staging chunk wv
  const int r1 = (wv + 4) * 16 + (lane >> 2);  // rows for staging chunk wv+4
  const int cc = (lane & 3) * 8;               // col (bf16) within 32-wide K tile
  const u16* Ab = A + (size_t)m0 * DMODEL;
  const u16* Wb = W + (size_t)n0 * DMODEL;

  for (int k0 = 0; k0 < DMODEL; k0 += 32){
    gload16(Ab + (size_t)r0 * DMODEL + k0 + cc, As + wv * 512);
    gload16(Ab + (size_t)r1 * DMODEL + k0 + cc, As + (wv + 4) * 512);
    gload16(Wb + (size_t)r0 * DMODEL + k0 + cc, Bs + wv * 512);
    gload16(Wb + (size_t)r1 * DMODEL + k0 + cc, Bs + (wv + 4) * 512);
    __syncthreads();

    bf16x8 af[4], bfr[4];
#pragma unroll
    for (int mi = 0; mi < 4; mi++)
      af[mi]  = *(const bf16x8*)(As + (wm * 64 + mi * 16 + l15) * 32 + lg * 8);
#pragma unroll
    for (int ni = 0; ni < 4; ni++)
      bfr[ni] = *(const bf16x8*)(Bs + (wn * 64 + ni * 16 + l15) * 32 + lg * 8);
#pragma unroll
    for (int mi = 0; mi < 4; mi++)
#pragma unroll
      for (int ni = 0; ni < 4; ni++)
        acc[mi][ni] = __builtin_amdgcn_mfma_f32_16x16x32_bf16(af[mi], bfr[ni], acc[mi][ni], 0, 0, 0);
    __syncthreads();
  }

#pragma unroll
  for (int mi = 0; mi < 4; mi++){
    int row = m0 + wm * 64 + mi * 16 + (lg << 2);
#pragma unroll
    for (int ni = 0; ni < 4; ni++){
      int col = n0 + wn * 64 + ni * 16 + l15;
      float bvv = bias[col];
#pragma unroll
      for (int r = 0; r < 4; r++)
        C[(size_t)(row + r) * DMODEL + col] = acc[mi][ni][r] + bvv;
    }
  }
}

__global__ __launch_bounds__(256) void gemm_qkv(const u16* __restrict__ xb,
    const u16* __restrict__ wqb, const u16* __restrict__ wkb, const u16* __restrict__ wvb,
    const float* __restrict__ bq, const float* __restrict__ bk, const float* __restrict__ bv,
    float* __restrict__ qf, float* __restrict__ kf, float* __restrict__ vf)
{
  __shared__ u16 As[128 * 32], Bs[128 * 32];
  int mt = blockIdx.x, nt = blockIdx.y;           // nt in [0,36)
  int sel = nt / 12, ntl = nt % 12;
  const u16* W = sel == 0 ? wqb : (sel == 1 ? wkb : wvb);
  const float* bias = sel == 0 ? bq : (sel == 1 ? bk : bv);
  float* C = sel == 0 ? qf : (sel == 1 ? kf : vf);
  gemm_core(xb, W, bias, C, mt * 128, ntl * 128, As, Bs);
}

__global__ __launch_bounds__(256) void gemm_o(const u16* __restrict__ ab,
    const u16* __restrict__ wob, const float* __restrict__ bo, float* __restrict__ out)
{
  __shared__ u16 As[128 * 32], Bs[128 * 32];
  gemm_core(ab, wob, bo, out, blockIdx.x * 128, blockIdx.y * 128, As, Bs);
}

// ---------------- fused RMSNorm + RoPE (q and k) ----------------
__global__ __launch_bounds__(256) void rmsrope_kernel(
    const float* __restrict__ qin, const float* __restrict__ kin,
    const float* __restrict__ gq, const float* __restrict__ gk,
    const float* __restrict__ fcos, const float* __restrict__ fsin,
    u16* __restrict__ rq, u16* __restrict__ rk)
{
  int s = blockIdx.x, t = threadIdx.x;
  int fi = s >> 8, hi2 = (s >> 4) & 15, wi = s & 15;
  __shared__ float red[4];

  for (int pass = 0; pass < 2; pass++){
    const float* in = pass ? kin : qin;
    const float* g  = pass ? gk  : gq;
    u16* outp       = pass ? rk  : rq;
    const float* row = in + (size_t)s * DMODEL;

    float v[6];
    float2 a = *(const float2*)(row + t * 6);
    float2 b = *(const float2*)(row + t * 6 + 2);
    float2 c = *(const float2*)(row + t * 6 + 4);
    v[0] = a.x; v[1] = a.y; v[2] = b.x; v[3] = b.y; v[4] = c.x; v[5] = c.y;

    float ss = 0.f;
#pragma unroll
    for (int j = 0; j < 6; j++) ss += v[j] * v[j];
#pragma unroll
    for (int m = 1; m < 64; m <<= 1) ss += __shfl_xor(ss, m);
    if ((t & 63) == 0) red[t >> 6] = ss;
    __syncthreads();
    float tot = red[0] + red[1] + red[2] + red[3];
    float scale = rsqrtf(tot * (1.0f / (float)DMODEL) + 1e-6f);

#pragma unroll
    for (int p = 0; p < 3; p++){
      int i  = t * 3 + p;          // global pair index
      int pi = i & 63;             // pair index within head
      int idx = pi < 22 ? fi : (pi < 43 ? hi2 : wi);
      float cv = fcos[idx * 64 + pi];
      float sv = fsin[idx * 64 + pi];
      int d = t * 6 + 2 * p;
      float xr = v[2 * p]     * scale * g[d];
      float xi = v[2 * p + 1] * scale * g[d + 1];
      outp[(size_t)s * DMODEL + d]     = f2bf(xr * cv - xi * sv);
      outp[(size_t)s * DMODEL + d + 1] = f2bf(xr * sv + xi * cv);
    }
    __syncthreads();
  }
}

// ---------------- V transpose: [SEQ][DMODEL] f32 -> [DMODEL][SEQ] bf16 ----------------
__global__ __launch_bounds__(256) void transpose_v(const float* __restrict__ vf, u16* __restrict__ vt)
{
  __shared__ float tile[32][33];
  int tx = threadIdx.x & 31, ty = threadIdx.x >> 5;   // 32 x 8
  int d0 = blockIdx.x * 32;
  int s0 = blockIdx.y * 32;
#pragma unroll
  for (int j = 0; j < 4; j++)
    tile[ty + j * 8][tx] = vf[(size_t)(s0 + ty + j * 8) * DMODEL + d0 + tx];
  __syncthreads();
#pragma unroll
  for (int j = 0; j < 4; j++)
    vt[(size_t)(d0 + ty + j * 8) * SEQ + s0 + tx] = f2bf(tile[tx][ty + j * 8]);
}

// ---------------- attention: per-wave 16-query tile, swapped QK^T ----------------
__global__ __launch_bounds__(256) void attn_kernel(const u16* __restrict__ rq,
    const u16* __restrict__ rk, const u16* __restrict__ vt, u16* __restrict__ ao)
{
  const int lane = threadIdx.x & 63;
  const int wv   = threadIdx.x >> 6;
  const int head = blockIdx.y;
  const int qt   = blockIdx.x * 4 + wv;    // 0..191
  const int q0   = qt * 16;
  const int qb   = q0 / 768;
  const int l15  = lane & 15, lg = lane >> 4;
  const float sc = 0.08838834764831845f;   // 1/sqrt(128)

  bf16x8 qfr[4];
  const u16* qbase = rq + (size_t)(q0 + l15) * DMODEL + head * HDIM + lg * 8;
#pragma unroll
  for (int c = 0; c < 4; c++) qfr[c] = *(const bf16x8*)(qbase + c * 32);

  f32x4 oacc[8];
#pragma unroll
  for (int i = 0; i < 8; i++){ f32x4 z = {0.f,0.f,0.f,0.f}; oacc[i] = z; }
  float m_run = -1e30f, l_run = 0.f;

  auto process = [&](int ks, int ke){
    for (int k0 = ks; k0 < ke; k0 += 32){
      const u16* kb0 = rk + (size_t)(k0 + l15) * DMODEL + head * HDIM + lg * 8;
      const u16* kb1 = kb0 + (size_t)16 * DMODEL;
      f32x4 s0 = {0.f,0.f,0.f,0.f}, s1 = {0.f,0.f,0.f,0.f};
#pragma unroll
      for (int c = 0; c < 4; c++){
        bf16x8 kf0 = *(const bf16x8*)(kb0 + c * 32);
        bf16x8 kf1 = *(const bf16x8*)(kb1 + c * 32);
        s0 = __builtin_amdgcn_mfma_f32_16x16x32_bf16(kf0, qfr[c], s0, 0, 0, 0);
        s1 = __builtin_amdgcn_mfma_f32_16x16x32_bf16(kf1, qfr[c], s1, 0, 0, 0);
      }
      float sm = -1e30f;
#pragma unroll
      for (int r = 0; r < 4; r++){
        s0[r] *= sc; s1[r] *= sc;
        sm = fmaxf(sm, fmaxf(s0[r], s1[r]));
      }
      sm = fmaxf(sm, __shfl_xor(sm, 16));
      sm = fmaxf(sm, __shfl_xor(sm, 32));
      float mn = fmaxf(m_run, sm);
      float corr = expf(m_run - mn);
      float ps0[4], ps1[4], psum = 0.f;
#pragma unroll
      for (int r = 0; r < 4; r++){
        ps0[r] = expf(s0[r] - mn);
        ps1[r] = expf(s1[r] - mn);
        psum += ps0[r] + ps1[r];
      }
      psum += __shfl_xor(psum, 16);
      psum += __shfl_xor(psum, 32);
      l_run = l_run * corr + psum;
      m_run = mn;

      float c4[4];
#pragma unroll
      for (int r = 0; r < 4; r++) c4[r] = __shfl(corr, lg * 4 + r);
#pragma unroll
      for (int ch = 0; ch < 8; ch++)
#pragma unroll
        for (int r = 0; r < 4; r++) oacc[ch][r] *= c4[r];

      bf16x8 pf;
#pragma unroll
      for (int r = 0; r < 4; r++){
        pf[r]     = (short)f2bf(ps0[r]);
        pf[r + 4] = (short)f2bf(ps1[r]);
      }
      const u16* vbase = vt + (size_t)(head * HDIM + l15) * SEQ + k0 + lg * 4;
#pragma unroll
      for (int ch = 0; ch < 8; ch++){
        const u16* vp = vbase + (size_t)(ch * 16) * SEQ;
        bf16x4 va = *(const bf16x4*)(vp);
        bf16x4 vb = *(const bf16x4*)(vp + 16);
        bf16x8 vf8;
        vf8[0] = va[0]; vf8[1] = va[1]; vf8[2] = va[2]; vf8[3] = va[3];
        vf8[4] = vb[0]; vf8[5] = vb[1]; vf8[6] = vb[2]; vf8[7] = vb[3];
        oacc[ch] = __builtin_amdgcn_mfma_f32_16x16x32_bf16(pf, vf8, oacc[ch], 0, 0, 0);
      }
    }
  };

  if      (qb == 0) process(0, 768);
  else if (qb == 1) process(0, 1536);
  else if (qb == 2){ process(0, 256); process(768, 2304); }
  else             { process(0, 256); process(1536, 3072); }

  float li[4];
#pragma unroll
  for (int r = 0; r < 4; r++) li[r] = 1.f / __shfl(l_run, lg * 4 + r);
#pragma unroll
  for (int ch = 0; ch < 8; ch++)
#pragma unroll
    for (int r = 0; r < 4; r++)
      ao[(size_t)(q0 + lg * 4 + r) * DMODEL + head * HDIM + ch * 16 + l15] =
          f2bf(oacc[ch][r] * li[r]);
}

// ---------------- launch ----------------
extern "C" void kernel_launch(void* const* d_in, const int* in_sizes, int n_in,
                              void* d_out, int out_size, void* d_ws, size_t ws_size,
                              hipStream_t stream)
{
  const float* x    = (const float*)d_in[0];
  const float* Wq   = (const float*)d_in[1];
  const float* bq   = (const float*)d_in[2];
  const float* Wk   = (const float*)d_in[3];
  const float* bk   = (const float*)d_in[4];
  const float* Wv   = (const float*)d_in[5];
  const float* bv   = (const float*)d_in[6];
  const float* Wo   = (const float*)d_in[7];
  const float* bo   = (const float*)d_in[8];
  const float* gq   = (const float*)d_in[9];
  const float* gk   = (const float*)d_in[10];
  const float* fcos = (const float*)d_in[11];
  const float* fsin = (const float*)d_in[12];
  float* out = (float*)d_out;

  char* ws = (char*)d_ws;
  size_t off = 0;
  auto alloc = [&](size_t bytes){
    void* p = ws + off;
    off += (bytes + 255) & ~(size_t)255;
    return p;
  };
  const size_t SD = (size_t)SEQ * DMODEL;
  const size_t WW = (size_t)DMODEL * DMODEL;
  u16*   xb  = (u16*)  alloc(SD * 2);
  u16*   wqb = (u16*)  alloc(WW * 2);
  u16*   wkb = (u16*)  alloc(WW * 2);
  u16*   wvb = (u16*)  alloc(WW * 2);
  u16*   wob = (u16*)  alloc(WW * 2);
  float* qf  = (float*)alloc(SD * 4);
  float* kf  = (float*)alloc(SD * 4);
  float* vf  = (float*)alloc(SD * 4);
  u16*   rq  = (u16*)  alloc(SD * 2);
  u16*   rk  = (u16*)  alloc(SD * 2);
  u16*   vt  = (u16*)  alloc(SD * 2);
  u16*   ao  = (u16*)  alloc(SD * 2);

  int nx4 = (int)(SD / 4), nw4 = (int)(WW / 4);
  cvt4_kernel<<<(nx4 + 255) / 256, 256, 0, stream>>>(x,  xb,  nx4);
  cvt4_kernel<<<(nw4 + 255) / 256, 256, 0, stream>>>(Wq, wqb, nw4);
  cvt4_kernel<<<(nw4 + 255) / 256, 256, 0, stream>>>(Wk, wkb, nw4);
  cvt4_kernel<<<(nw4 + 255) / 256, 256, 0, stream>>>(Wv, wvb, nw4);
  cvt4_kernel<<<(nw4 + 255) / 256, 256, 0, stream>>>(Wo, wob, nw4);

  gemm_qkv<<<dim3(SEQ / 128, 36), 256, 0, stream>>>(xb, wqb, wkb, wvb, bq, bk, bv, qf, kf, vf);
  rmsrope_kernel<<<SEQ, 256, 0, stream>>>(qf, kf, gq, gk, fcos, fsin, rq, rk);
  transpose_v<<<dim3(DMODEL / 32, SEQ / 32), 256, 0, stream>>>(vf, vt);
  attn_kernel<<<dim3(48, NHEAD), 256, 0, stream>>>(rq, rk, vt, ao);
  gemm_o<<<dim3(SEQ / 128, DMODEL / 128), 256, 0, stream>>>(ao, wob, bo, out);
}

// Round 2
// 372.108 us; speedup vs baseline: 1.8189x; 1.8189x over previous
//
#include <hip/hip_runtime.h>
#include <stdint.h>

typedef unsigned short u16;
typedef __attribute__((ext_vector_type(8))) short bf16x8;
typedef __attribute__((ext_vector_type(4))) short bf16x4;
typedef __attribute__((ext_vector_type(4))) float f32x4;

constexpr int DMODEL = 1536;
constexpr int SEQ    = 3072;
constexpr int NHEAD  = 12;
constexpr int HDIM   = 128;

__device__ __forceinline__ u16 f2bf(float f){
  union { float f; unsigned u; } v; v.f = f;
  return (u16)((v.u + 0x7fffu + ((v.u >> 16) & 1u)) >> 16);
}

// ---------------- convert f32 -> bf16 ----------------
__global__ __launch_bounds__(256) void cvt4_kernel(const float* __restrict__ src,
                                                   u16* __restrict__ dst, int n4){
  int i = blockIdx.x * 256 + threadIdx.x;
  if (i < n4){
    float4 f = ((const float4*)src)[i];
    ushort4 o;
    o.x = f2bf(f.x); o.y = f2bf(f.y); o.z = f2bf(f.z); o.w = f2bf(f.w);
    ((ushort4*)dst)[i] = o;
  }
}

// ---------------- GEMM core: C[128x128] = A[128xK] * W[128xK]^T + bias ----------------
__device__ __forceinline__ void gload16(const u16* g, u16* l){
  __builtin_amdgcn_global_load_lds((const __attribute__((address_space(1))) void*)g,
                                   (__attribute__((address_space(3))) void*)l, 16, 0, 0);
}

__device__ __forceinline__ void gemm_core(const u16* __restrict__ A, const u16* __restrict__ W,
    const float* __restrict__ bias, float* __restrict__ C, int m0, int n0,
    u16* As, u16* Bs)
{
  const int tid  = threadIdx.x;
  const int lane = tid & 63;
  const int wv   = tid >> 6;          // 0..3
  const int wm   = wv & 1, wn = wv >> 1;
  const int l15  = lane & 15, lg = lane >> 4;

  f32x4 acc[4][4];
#pragma unroll
  for (int i = 0; i < 4; i++)
#pragma unroll
    for (int j = 0; j < 4; j++){ f32x4 z = {0.f,0.f,0.f,0.f}; acc[i][j] = z; }

  const int r0 = wv * 16 + (lane >> 2);        // rows for staging chunk wv
  const int r1 = (wv + 4) * 16 + (lane >> 2);  // rows for staging chunk wv+4
  const int cc = (lane & 3) * 8;               // col (bf16) within 32-wide K tile
  const u16* Ab = A + (size_t)m0 * DMODEL;
  const u16* Wb = W + (size_t)n0 * DMODEL;

  for (int k0 = 0; k0 < DMODEL; k0 += 32){
    gload16(Ab + (size_t)r0 * DMODEL + k0 + cc, As + wv * 512);
    gload16(Ab + (size_t)r1 * DMODEL + k0 + cc, As + (wv + 4) * 512);
    gload16(Wb + (size_t)r0 * DMODEL + k0 + cc, Bs + wv * 512);
    gload16(Wb + (size_t)r1 * DMODEL + k0 + cc, Bs + (wv + 4) * 512);
    __syncthreads();

    bf16x8 af[4], bfr[4];
#pragma unroll
    for (int mi = 0; mi < 4; mi++)
      af[mi]  = *(const bf16x8*)(As + (wm * 64 + mi * 16 + l15) * 32 + lg * 8);
#pragma unroll
    for (int ni = 0; ni < 4; ni++)
      bfr[ni] = *(const bf16x8*)(Bs + (wn * 64 + ni * 16 + l15) * 32 + lg * 8);
#pragma unroll
    for (int mi = 0; mi < 4; mi++)
#pragma unroll
      for (int ni = 0; ni < 4; ni++)
        acc[mi][ni] = __builtin_amdgcn_mfma_f32_16x16x32_bf16(af[mi], bfr[ni], acc[mi][ni], 0, 0, 0);
    __syncthreads();
  }

#pragma unroll
  for (int mi = 0; mi < 4; mi++){
    int row = m0 + wm * 64 + mi * 16 + (lg << 2);
#pragma unroll
    for (int ni = 0; ni < 4; ni++){
      int col = n0 + wn * 64 + ni * 16 + l15;
      float bvv = bias[col];
#pragma unroll
      for (int r = 0; r < 4; r++)
        C[(size_t)(row + r) * DMODEL + col] = acc[mi][ni][r] + bvv;
    }
  }
}

__global__ __launch_bounds__(256) void gemm_qkv(const u16* __restrict__ xb,
    const u16* __restrict__ wqb, const u16* __restrict__ wkb, const u16* __restrict__ wvb,
    const float* __restrict__ bq, const float* __restrict__ bk, const float* __restrict__ bv,
    float* __restrict__ qf, float* __restrict__ kf, float* __restrict__ vf)
{
  __shared__ u16 As[128 * 32], Bs[128 * 32];
  int mt = blockIdx.x, nt = blockIdx.y;           // nt in [0,36)
  int sel = nt / 12, ntl = nt % 12;
  const u16* W = sel == 0 ? wqb : (sel == 1 ? wkb : wvb);
  const float* bias = sel == 0 ? bq : (sel == 1 ? bk : bv);
  float* C = sel == 0 ? qf : (sel == 1 ? kf : vf);
  gemm_core(xb, W, bias, C, mt * 128, ntl * 128, As, Bs);
}

__global__ __launch_bounds__(256) void gemm_o(const u16* __restrict__ ab,
    const u16* __restrict__ wob, const float* __restrict__ bo, float* __restrict__ out)
{
  __shared__ u16 As[128 * 32], Bs[128 * 32];
  gemm_core(ab, wob, bo, out, blockIdx.x * 128, blockIdx.y * 128, As, Bs);
}

// ---------------- fused RMSNorm + RoPE (q and k) ----------------
__global__ __launch_bounds__(256) void rmsrope_kernel(
    const float* __restrict__ qin, const float* __restrict__ kin,
    const float* __restrict__ gq, const float* __restrict__ gk,
    const float* __restrict__ fcos, const float* __restrict__ fsin,
    u16* __restrict__ rq, u16* __restrict__ rk)
{
  int s = blockIdx.x, t = threadIdx.x;
  int fi = s >> 8, hi2 = (s >> 4) & 15, wi = s & 15;
  __shared__ float red[4];

  for (int pass = 0; pass < 2; pass++){
    const float* in = pass ? kin : qin;
    const float* g  = pass ? gk  : gq;
    u16* outp       = pass ? rk  : rq;
    const float* row = in + (size_t)s * DMODEL;

    float v[6];
    float2 a = *(const float2*)(row + t * 6);
    float2 b = *(const float2*)(row + t * 6 + 2);
    float2 c = *(const float2*)(row + t * 6 + 4);
    v[0] = a.x; v[1] = a.y; v[2] = b.x; v[3] = b.y; v[4] = c.x; v[5] = c.y;

    float ss = 0.f;
#pragma unroll
    for (int j = 0; j < 6; j++) ss += v[j] * v[j];
#pragma unroll
    for (int m = 1; m < 64; m <<= 1) ss += __shfl_xor(ss, m);
    if ((t & 63) == 0) red[t >> 6] = ss;
    __syncthreads();
    float tot = red[0] + red[1] + red[2] + red[3];
    float scale = rsqrtf(tot * (1.0f / (float)DMODEL) + 1e-6f);

#pragma unroll
    for (int p = 0; p < 3; p++){
      int i  = t * 3 + p;          // global pair index
      int pi = i & 63;             // pair index within head
      int idx = pi < 22 ? fi : (pi < 43 ? hi2 : wi);
      float cv = fcos[idx * 64 + pi];
      float sv = fsin[idx * 64 + pi];
      int d = t * 6 + 2 * p;
      float xr = v[2 * p]     * scale * g[d];
      float xi = v[2 * p + 1] * scale * g[d + 1];
      outp[(size_t)s * DMODEL + d]     = f2bf(xr * cv - xi * sv);
      outp[(size_t)s * DMODEL + d + 1] = f2bf(xr * sv + xi * cv);
    }
    __syncthreads();
  }
}

// ---------------- V transpose: [SEQ][DMODEL] f32 -> [DMODEL][SEQ] bf16 ----------------
__global__ __launch_bounds__(256) void transpose_v(const float* __restrict__ vf, u16* __restrict__ vt)
{
  __shared__ float tile[32][33];
  int tx = threadIdx.x & 31, ty = threadIdx.x >> 5;   // 32 x 8
  int d0 = blockIdx.x * 32;
  int s0 = blockIdx.y * 32;
#pragma unroll
  for (int j = 0; j < 4; j++)
    tile[ty + j * 8][tx] = vf[(size_t)(s0 + ty + j * 8) * DMODEL + d0 + tx];
  __syncthreads();
#pragma unroll
  for (int j = 0; j < 4; j++)
    vt[(size_t)(d0 + ty + j * 8) * SEQ + s0 + tx] = f2bf(tile[tx][ty + j * 8]);
}

// ---------------- attention v2: LDS-staged K/V, double-buffered, 4 waves/block ----------------
// Block = 64 queries x 1 head. Wave wv owns queries [q0, q0+16).
// K tile [64 keys][128 dims] bf16 (16KB), V tile [128 dims][64 keys] bf16 (16KB),
// both XOR-swizzled (byte ^= (row&7)<<4) with inverse-swizzled global source
// (rule 21: linear LDS dest for global_load_lds, same involution on read).
__global__ __launch_bounds__(256, 2) void attn_kernel(const u16* __restrict__ rq,
    const u16* __restrict__ rk, const u16* __restrict__ vt, u16* __restrict__ ao)
{
  __shared__ u16 Ks[2][8192];
  __shared__ u16 Vs[2][8192];

  const int tid  = threadIdx.x;
  const int lane = tid & 63;
  const int wv   = tid >> 6;
  const int head = blockIdx.y;
  const int q0   = blockIdx.x * 64 + wv * 16;
  const int qb   = blockIdx.x / 12;          // 768-token block index
  const int l15  = lane & 15, lg = lane >> 4;
  const int swz  = (l15 & 7) << 4;
  const float sc = 0.08838834764831845f;     // 1/sqrt(128)

  // key ranges (block-granular mask; all boundaries multiples of 64)
  int r0s = 0, r0e = 0, r1s = 0, r1e = 0;
  if      (qb == 0){ r0e = 768; }
  else if (qb == 1){ r0e = 1536; }
  else if (qb == 2){ r0e = 256; r1s = 768;  r1e = 2304; }
  else             { r0e = 256; r1s = 1536; r1e = 3072; }
  const int nt0 = (r0e - r0s) >> 6;
  const int nt  = nt0 + ((r1e - r1s) >> 6);

  const char* rkB = (const char*)rk;
  const char* vtB = (const char*)vt;

  auto k0_of = [&](int t){ return t < nt0 ? (r0s + t * 64) : (r1s + (t - nt0) * 64); };

  auto stage = [&](int buf, int k0){
    char* Kd = (char*)Ks[buf];
    char* Vd = (char*)Vs[buf];
#pragma unroll
    for (int c = 0; c < 4; c++){
      int o = c * 4096 + wv * 1024 + lane * 16;
      int row = o >> 8, colb = o & 255;
      gload16((const u16*)(rkB + (size_t)(k0 + row) * (DMODEL * 2) + head * (HDIM * 2)
                               + (colb ^ ((row & 7) << 4))),
              (u16*)(Kd + c * 4096 + wv * 1024));
    }
#pragma unroll
    for (int c = 0; c < 4; c++){
      int o = c * 4096 + wv * 1024 + lane * 16;
      int row = o >> 7, colb = o & 127;
      gload16((const u16*)(vtB + (size_t)(head * HDIM + row) * (SEQ * 2) + (size_t)k0 * 2
                               + (colb ^ ((row & 7) << 4))),
              (u16*)(Vd + c * 4096 + wv * 1024));
    }
  };

  // Q fragments (register-resident)
  bf16x8 qfr[4];
  const u16* qbase = rq + (size_t)(q0 + l15) * DMODEL + head * HDIM + lg * 8;
#pragma unroll
  for (int c = 0; c < 4; c++) qfr[c] = *(const bf16x8*)(qbase + c * 32);

  f32x4 oacc[8];
#pragma unroll
  for (int i = 0; i < 8; i++){ f32x4 z = {0.f,0.f,0.f,0.f}; oacc[i] = z; }
  float m_run = -1e30f, l_run = 0.f;

  stage(0, k0_of(0));
  __syncthreads();

  for (int t = 0; t < nt; t++){
    int buf = t & 1;
    if (t + 1 < nt) stage(buf ^ 1, k0_of(t + 1));

    const char* Kb = (const char*)Ks[buf];
    const char* Vb = (const char*)Vs[buf];
#pragma unroll
    for (int half = 0; half < 2; half++){
      const int kt = half * 32;
      const char* kr0 = Kb + (kt + l15) * 256;
      const char* kr1 = Kb + (kt + 16 + l15) * 256;
      bf16x8 kf0[4], kf1[4];
#pragma unroll
      for (int c = 0; c < 4; c++){
        kf0[c] = *(const bf16x8*)(kr0 + ((lg * 16 + c * 64) ^ swz));
        kf1[c] = *(const bf16x8*)(kr1 + ((lg * 16 + c * 64) ^ swz));
      }
      f32x4 s0 = {0.f,0.f,0.f,0.f}, s1 = {0.f,0.f,0.f,0.f};
      __builtin_amdgcn_s_setprio(1);
#pragma unroll
      for (int c = 0; c < 4; c++){
        s0 = __builtin_amdgcn_mfma_f32_16x16x32_bf16(kf0[c], qfr[c], s0, 0, 0, 0);
        s1 = __builtin_amdgcn_mfma_f32_16x16x32_bf16(kf1[c], qfr[c], s1, 0, 0, 0);
      }
      __builtin_amdgcn_s_setprio(0);

      float sm = -1e30f;
#pragma unroll
      for (int r = 0; r < 4; r++){
        s0[r] *= sc; s1[r] *= sc;
        sm = fmaxf(sm, fmaxf(s0[r], s1[r]));
      }
      sm = fmaxf(sm, __shfl_xor(sm, 16));
      sm = fmaxf(sm, __shfl_xor(sm, 32));
      float mn = fmaxf(m_run, sm);
      float corr = __expf(m_run - mn);
      float ps0[4], ps1[4], psum = 0.f;
#pragma unroll
      for (int r = 0; r < 4; r++){
        ps0[r] = __expf(s0[r] - mn);
        ps1[r] = __expf(s1[r] - mn);
        psum += ps0[r] + ps1[r];
      }
      psum += __shfl_xor(psum, 16);
      psum += __shfl_xor(psum, 32);
      l_run = l_run * corr + psum;
      m_run = mn;

      float c4[4];
#pragma unroll
      for (int r = 0; r < 4; r++) c4[r] = __shfl(corr, lg * 4 + r);
#pragma unroll
      for (int ch = 0; ch < 8; ch++)
#pragma unroll
        for (int r = 0; r < 4; r++) oacc[ch][r] *= c4[r];

      bf16x8 pf;
#pragma unroll
      for (int r = 0; r < 4; r++){
        pf[r]     = (short)f2bf(ps0[r]);
        pf[r + 4] = (short)f2bf(ps1[r]);
      }
      __builtin_amdgcn_s_setprio(1);
#pragma unroll
      for (int ch = 0; ch < 8; ch++){
        const char* vr = Vb + (ch * 16 + l15) * 128;
        const int cb = kt * 2 + lg * 8;
        bf16x4 va = *(const bf16x4*)(vr + (cb ^ swz));
        bf16x4 vb2 = *(const bf16x4*)(vr + ((cb + 32) ^ swz));
        bf16x8 vf8;
        vf8[0] = va[0]; vf8[1] = va[1]; vf8[2] = va[2]; vf8[3] = va[3];
        vf8[4] = vb2[0]; vf8[5] = vb2[1]; vf8[6] = vb2[2]; vf8[7] = vb2[3];
        oacc[ch] = __builtin_amdgcn_mfma_f32_16x16x32_bf16(pf, vf8, oacc[ch], 0, 0, 0);
      }
      __builtin_amdgcn_s_setprio(0);
    }
    __syncthreads();   // drains prefetch (vmcnt) + publishes next buffer
  }

  float li[4];
#pragma unroll
  for (int r = 0; r < 4; r++) li[r] = 1.f / __shfl(l_run, lg * 4 + r);
#pragma unroll
  for (int ch = 0; ch < 8; ch++)
#pragma unroll
    for (int r = 0; r < 4; r++)
      ao[(size_t)(q0 + lg * 4 + r) * DMODEL + head * HDIM + ch * 16 + l15] =
          f2bf(oacc[ch][r] * li[r]);
}

// ---------------- launch ----------------
extern "C" void kernel_launch(void* const* d_in, const int* in_sizes, int n_in,
                              void* d_out, int out_size, void* d_ws, size_t ws_size,
                              hipStream_t stream)
{
  const float* x    = (const float*)d_in[0];
  const float* Wq   = (const float*)d_in[1];
  const float* bq   = (const float*)d_in[2];
  const float* Wk   = (const float*)d_in[3];
  const float* bk   = (const float*)d_in[4];
  const float* Wv   = (const float*)d_in[5];
  const float* bv   = (const float*)d_in[6];
  const float* Wo   = (const float*)d_in[7];
  const float* bo   = (const float*)d_in[8];
  const float* gq   = (const float*)d_in[9];
  const float* gk   = (const float*)d_in[10];
  const float* fcos = (const float*)d_in[11];
  const float* fsin = (const float*)d_in[12];
  float* out = (float*)d_out;

  char* ws = (char*)d_ws;
  size_t off = 0;
  auto alloc = [&](size_t bytes){
    void* p = ws + off;
    off += (bytes + 255) & ~(size_t)255;
    return p;
  };
  const size_t SD = (size_t)SEQ * DMODEL;
  const size_t WW = (size_t)DMODEL * DMODEL;
  u16*   xb  = (u16*)  alloc(SD * 2);
  u16*   wqb = (u16*)  alloc(WW * 2);
  u16*   wkb = (u16*)  alloc(WW * 2);
  u16*   wvb = (u16*)  alloc(WW * 2);
  u16*   wob = (u16*)  alloc(WW * 2);
  float* qf  = (float*)alloc(SD * 4);
  float* kf  = (float*)alloc(SD * 4);
  float* vf  = (float*)alloc(SD * 4);
  u16*   rq  = (u16*)  alloc(SD * 2);
  u16*   rk  = (u16*)  alloc(SD * 2);
  u16*   vt  = (u16*)  alloc(SD * 2);
  u16*   ao  = (u16*)  alloc(SD * 2);

  int nx4 = (int)(SD / 4), nw4 = (int)(WW / 4);
  cvt4_kernel<<<(nx4 + 255) / 256, 256, 0, stream>>>(x,  xb,  nx4);
  cvt4_kernel<<<(nw4 + 255) / 256, 256, 0, stream>>>(Wq, wqb, nw4);
  cvt4_kernel<<<(nw4 + 255) / 256, 256, 0, stream>>>(Wk, wkb, nw4);
  cvt4_kernel<<<(nw4 + 255) / 256, 256, 0, stream>>>(Wv, wvb, nw4);
  cvt4_kernel<<<(nw4 + 255) / 256, 256, 0, stream>>>(Wo, wob, nw4);

  gemm_qkv<<<dim3(SEQ / 128, 36), 256, 0, stream>>>(xb, wqb, wkb, wvb, bq, bk, bv, qf, kf, vf);
  rmsrope_kernel<<<SEQ, 256, 0, stream>>>(qf, kf, gq, gk, fcos, fsin, rq, rk);
  transpose_v<<<dim3(DMODEL / 32, SEQ / 32), 256, 0, stream>>>(vf, vt);
  attn_kernel<<<dim3(SEQ / 64, NHEAD), 256, 0, stream>>>(rq, rk, vt, ao);
  gemm_o<<<dim3(SEQ / 128, DMODEL / 128), 256, 0, stream>>>(ao, wob, bo, out);
}

// Round 3
// 339.263 us; speedup vs baseline: 1.9950x; 1.0968x over previous
//
#include <hip/hip_runtime.h>
#include <stdint.h>

typedef unsigned short u16;
typedef __attribute__((ext_vector_type(8))) short bf16x8;
typedef __attribute__((ext_vector_type(4))) short bf16x4;
typedef __attribute__((ext_vector_type(4))) float f32x4;

constexpr int DMODEL = 1536;
constexpr int SEQ    = 3072;
constexpr int NHEAD  = 12;
constexpr int HDIM   = 128;

__device__ __forceinline__ u16 f2bf(float f){
  union { float f; unsigned u; } v; v.f = f;
  return (u16)((v.u + 0x7fffu + ((v.u >> 16) & 1u)) >> 16);
}

// ---------------- convert f32 -> bf16 ----------------
__global__ __launch_bounds__(256) void cvt4_kernel(const float* __restrict__ src,
                                                   u16* __restrict__ dst, int n4){
  int i = blockIdx.x * 256 + threadIdx.x;
  if (i < n4){
    float4 f = ((const float4*)src)[i];
    ushort4 o;
    o.x = f2bf(f.x); o.y = f2bf(f.y); o.z = f2bf(f.z); o.w = f2bf(f.w);
    ((ushort4*)dst)[i] = o;
  }
}

// ---------------- GEMM core: C[128x128] = A[128xK] * W[128xK]^T + bias ----------------
__device__ __forceinline__ void gload16(const u16* g, u16* l){
  __builtin_amdgcn_global_load_lds((const __attribute__((address_space(1))) void*)g,
                                   (__attribute__((address_space(3))) void*)l, 16, 0, 0);
}

__device__ __forceinline__ void gemm_core(const u16* __restrict__ A, const u16* __restrict__ W,
    const float* __restrict__ bias, float* __restrict__ C, int m0, int n0,
    u16* As, u16* Bs)
{
  const int tid  = threadIdx.x;
  const int lane = tid & 63;
  const int wv   = tid >> 6;          // 0..3
  const int wm   = wv & 1, wn = wv >> 1;
  const int l15  = lane & 15, lg = lane >> 4;

  f32x4 acc[4][4];
#pragma unroll
  for (int i = 0; i < 4; i++)
#pragma unroll
    for (int j = 0; j < 4; j++){ f32x4 z = {0.f,0.f,0.f,0.f}; acc[i][j] = z; }

  const int r0 = wv * 16 + (lane >> 2);        // rows for staging chunk wv
  const int r1 = (wv + 4) * 16 + (lane >> 2);  // rows for staging chunk wv+4
  const int cc = (lane & 3) * 8;               // col (bf16) within 32-wide K tile
  const u16* Ab = A + (size_t)m0 * DMODEL;
  const u16* Wb = W + (size_t)n0 * DMODEL;

  for (int k0 = 0; k0 < DMODEL; k0 += 32){
    gload16(Ab + (size_t)r0 * DMODEL + k0 + cc, As + wv * 512);
    gload16(Ab + (size_t)r1 * DMODEL + k0 + cc, As + (wv + 4) * 512);
    gload16(Wb + (size_t)r0 * DMODEL + k0 + cc, Bs + wv * 512);
    gload16(Wb + (size_t)r1 * DMODEL + k0 + cc, Bs + (wv + 4) * 512);
    __syncthreads();

    bf16x8 af[4], bfr[4];
#pragma unroll
    for (int mi = 0; mi < 4; mi++)
      af[mi]  = *(const bf16x8*)(As + (wm * 64 + mi * 16 + l15) * 32 + lg * 8);
#pragma unroll
    for (int ni = 0; ni < 4; ni++)
      bfr[ni] = *(const bf16x8*)(Bs + (wn * 64 + ni * 16 + l15) * 32 + lg * 8);
#pragma unroll
    for (int mi = 0; mi < 4; mi++)
#pragma unroll
      for (int ni = 0; ni < 4; ni++)
        acc[mi][ni] = __builtin_amdgcn_mfma_f32_16x16x32_bf16(af[mi], bfr[ni], acc[mi][ni], 0, 0, 0);
    __syncthreads();
  }

#pragma unroll
  for (int mi = 0; mi < 4; mi++){
    int row = m0 + wm * 64 + mi * 16 + (lg << 2);
#pragma unroll
    for (int ni = 0; ni < 4; ni++){
      int col = n0 + wn * 64 + ni * 16 + l15;
      float bvv = bias[col];
#pragma unroll
      for (int r = 0; r < 4; r++)
        C[(size_t)(row + r) * DMODEL + col] = acc[mi][ni][r] + bvv;
    }
  }
}

__global__ __launch_bounds__(256) void gemm_qkv(const u16* __restrict__ xb,
    const u16* __restrict__ wqb, const u16* __restrict__ wkb, const u16* __restrict__ wvb,
    const float* __restrict__ bq, const float* __restrict__ bk, const float* __restrict__ bv,
    float* __restrict__ qf, float* __restrict__ kf, float* __restrict__ vf)
{
  __shared__ u16 As[128 * 32], Bs[128 * 32];
  int mt = blockIdx.x, nt = blockIdx.y;           // nt in [0,36)
  int sel = nt / 12, ntl = nt % 12;
  const u16* W = sel == 0 ? wqb : (sel == 1 ? wkb : wvb);
  const float* bias = sel == 0 ? bq : (sel == 1 ? bk : bv);
  float* C = sel == 0 ? qf : (sel == 1 ? kf : vf);
  gemm_core(xb, W, bias, C, mt * 128, ntl * 128, As, Bs);
}

__global__ __launch_bounds__(256) void gemm_o(const u16* __restrict__ ab,
    const u16* __restrict__ wob, const float* __restrict__ bo, float* __restrict__ out)
{
  __shared__ u16 As[128 * 32], Bs[128 * 32];
  gemm_core(ab, wob, bo, out, blockIdx.x * 128, blockIdx.y * 128, As, Bs);
}

// ---------------- fused RMSNorm + RoPE (q and k) ----------------
__global__ __launch_bounds__(256) void rmsrope_kernel(
    const float* __restrict__ qin, const float* __restrict__ kin,
    const float* __restrict__ gq, const float* __restrict__ gk,
    const float* __restrict__ fcos, const float* __restrict__ fsin,
    u16* __restrict__ rq, u16* __restrict__ rk)
{
  int s = blockIdx.x, t = threadIdx.x;
  int fi = s >> 8, hi2 = (s >> 4) & 15, wi = s & 15;
  __shared__ float red[4];

  for (int pass = 0; pass < 2; pass++){
    const float* in = pass ? kin : qin;
    const float* g  = pass ? gk  : gq;
    u16* outp       = pass ? rk  : rq;
    const float* row = in + (size_t)s * DMODEL;

    float v[6];
    float2 a = *(const float2*)(row + t * 6);
    float2 b = *(const float2*)(row + t * 6 + 2);
    float2 c = *(const float2*)(row + t * 6 + 4);
    v[0] = a.x; v[1] = a.y; v[2] = b.x; v[3] = b.y; v[4] = c.x; v[5] = c.y;

    float ss = 0.f;
#pragma unroll
    for (int j = 0; j < 6; j++) ss += v[j] * v[j];
#pragma unroll
    for (int m = 1; m < 64; m <<= 1) ss += __shfl_xor(ss, m);
    if ((t & 63) == 0) red[t >> 6] = ss;
    __syncthreads();
    float tot = red[0] + red[1] + red[2] + red[3];
    float scale = rsqrtf(tot * (1.0f / (float)DMODEL) + 1e-6f);

#pragma unroll
    for (int p = 0; p < 3; p++){
      int i  = t * 3 + p;          // global pair index
      int pi = i & 63;             // pair index within head
      int idx = pi < 22 ? fi : (pi < 43 ? hi2 : wi);
      float cv = fcos[idx * 64 + pi];
      float sv = fsin[idx * 64 + pi];
      int d = t * 6 + 2 * p;
      float xr = v[2 * p]     * scale * g[d];
      float xi = v[2 * p + 1] * scale * g[d + 1];
      outp[(size_t)s * DMODEL + d]     = f2bf(xr * cv - xi * sv);
      outp[(size_t)s * DMODEL + d + 1] = f2bf(xr * sv + xi * cv);
    }
    __syncthreads();
  }
}

// ---------------- V transpose: [SEQ][DMODEL] f32 -> [DMODEL][SEQ] bf16, key-permuted ----------------
// Within each 32-key group, key k stored at p(k) = ((k&15)>>2)*8 + ((k>>4)&1)*4 + (k&3),
// matching the attention pf slot->key bijection so each V fragment is ONE ds_read_b128.
__global__ __launch_bounds__(256) void transpose_v(const float* __restrict__ vf, u16* __restrict__ vt)
{
  __shared__ float tile[32][33];
  int tx = threadIdx.x & 31, ty = threadIdx.x >> 5;   // 32 x 8
  int d0 = blockIdx.x * 32;
  int s0 = blockIdx.y * 32;
#pragma unroll
  for (int j = 0; j < 4; j++)
    tile[ty + j * 8][tx] = vf[(size_t)(s0 + ty + j * 8) * DMODEL + d0 + tx];
  __syncthreads();
  int px = ((tx & 15) >> 2) * 8 + ((tx >> 4) & 1) * 4 + (tx & 3);
#pragma unroll
  for (int j = 0; j < 4; j++)
    vt[(size_t)(d0 + ty + j * 8) * SEQ + s0 + px] = f2bf(tile[tx][ty + j * 8]);
}

// ---------------- attention v3: fixed-max softmax, LDS double-buffered K/V ----------------
// Block = 64 queries x 1 head, 4 waves (16 q each). Scores bounded: |q.k|/sqrt(128) <= ~11.5
// (RMS-normed q,k; RoPE preserves norms) -> P = exp(s*sc - 12), no running max, no rescale.
// l_run = per-lane partial sums, reduced once at the end. K tile [64][128] and V tile
// [128][64] (key-permuted), both XOR-swizzled byte^=(row&7)<<4; all reads ds_read_b128,
// conflict-free. Longest-range blocks dispatched first for load balance.
__global__ __launch_bounds__(256, 2) void attn_kernel(const u16* __restrict__ rq,
    const u16* __restrict__ rk, const u16* __restrict__ vt, u16* __restrict__ ao)
{
  __shared__ u16 Ks[2][8192];
  __shared__ u16 Vs[2][8192];

  const int tid  = threadIdx.x;
  const int lane = tid & 63;
  const int wv   = tid >> 6;
  const int head = blockIdx.y;
  const int grp  = blockIdx.x / 12;          // longest-first remap: qb3,qb2,qb1,qb0
  const int rem  = blockIdx.x - grp * 12;
  const int qb   = 3 - grp;
  const int q_i  = qb * 12 + rem;
  const int q0   = q_i * 64 + wv * 16;
  const int l15  = lane & 15, lg = lane >> 4;
  const int swz  = (l15 & 7) << 4;
  const float sc = 0.08838834764831845f;     // 1/sqrt(128)

  // key ranges (block-granular mask; all boundaries multiples of 64)
  int r0s = 0, r0e = 0, r1s = 0, r1e = 0;
  if      (qb == 0){ r0e = 768; }
  else if (qb == 1){ r0e = 1536; }
  else if (qb == 2){ r0e = 256; r1s = 768;  r1e = 2304; }
  else             { r0e = 256; r1s = 1536; r1e = 3072; }
  const int nt0 = (r0e - r0s) >> 6;
  const int nt  = nt0 + ((r1e - r1s) >> 6);

  const char* rkB = (const char*)rk;
  const char* vtB = (const char*)vt;

  auto k0_of = [&](int t){ return t < nt0 ? (r0s + t * 64) : (r1s + (t - nt0) * 64); };

  auto stage = [&](int buf, int k0){
    char* Kd = (char*)Ks[buf];
    char* Vd = (char*)Vs[buf];
#pragma unroll
    for (int c = 0; c < 4; c++){
      int o = c * 4096 + wv * 1024 + lane * 16;
      int row = o >> 8, colb = o & 255;
      gload16((const u16*)(rkB + (size_t)(k0 + row) * (DMODEL * 2) + head * (HDIM * 2)
                               + (colb ^ ((row & 7) << 4))),
              (u16*)(Kd + c * 4096 + wv * 1024));
    }
#pragma unroll
    for (int c = 0; c < 4; c++){
      int o = c * 4096 + wv * 1024 + lane * 16;
      int row = o >> 7, colb = o & 127;
      gload16((const u16*)(vtB + (size_t)(head * HDIM + row) * (SEQ * 2) + (size_t)k0 * 2
                               + (colb ^ ((row & 7) << 4))),
              (u16*)(Vd + c * 4096 + wv * 1024));
    }
  };

  // Q fragments (register-resident)
  bf16x8 qfr[4];
  const u16* qbase = rq + (size_t)(q0 + l15) * DMODEL + head * HDIM + lg * 8;
#pragma unroll
  for (int c = 0; c < 4; c++) qfr[c] = *(const bf16x8*)(qbase + c * 32);

  f32x4 oacc[8];
#pragma unroll
  for (int i = 0; i < 8; i++){ f32x4 z = {0.f,0.f,0.f,0.f}; oacc[i] = z; }
  float l_run = 0.f;

  stage(0, k0_of(0));
  __syncthreads();

  for (int t = 0; t < nt; t++){
    int buf = t & 1;
    if (t + 1 < nt) stage(buf ^ 1, k0_of(t + 1));

    const char* Kb = (const char*)Ks[buf];
    const char* Vb = (const char*)Vs[buf];
#pragma unroll
    for (int half = 0; half < 2; half++){
      const int kt = half * 32;
      const char* kr0 = Kb + (kt + l15) * 256;
      const char* kr1 = kr0 + 16 * 256;
      bf16x8 kf0[4], kf1[4];
#pragma unroll
      for (int c = 0; c < 4; c++){
        kf0[c] = *(const bf16x8*)(kr0 + ((lg * 16 + c * 64) ^ swz));
        kf1[c] = *(const bf16x8*)(kr1 + ((lg * 16 + c * 64) ^ swz));
      }
      f32x4 s0 = {0.f,0.f,0.f,0.f}, s1 = {0.f,0.f,0.f,0.f};
      __builtin_amdgcn_s_setprio(1);
#pragma unroll
      for (int c = 0; c < 4; c++){
        s0 = __builtin_amdgcn_mfma_f32_16x16x32_bf16(kf0[c], qfr[c], s0, 0, 0, 0);
        s1 = __builtin_amdgcn_mfma_f32_16x16x32_bf16(kf1[c], qfr[c], s1, 0, 0, 0);
      }
      __builtin_amdgcn_s_setprio(0);

      // fixed-max softmax: P = exp(s*sc - 12); no cross-lane ops, no rescale
      bf16x8 pf;
      float lsum = 0.f;
#pragma unroll
      for (int r = 0; r < 4; r++){
        float e0 = __expf(fmaf(s0[r], sc, -12.f));
        float e1 = __expf(fmaf(s1[r], sc, -12.f));
        lsum += e0 + e1;
        pf[r]     = (short)f2bf(e0);
        pf[r + 4] = (short)f2bf(e1);
      }
      l_run += lsum;

      __builtin_amdgcn_s_setprio(1);
#pragma unroll
      for (int ch = 0; ch < 8; ch++){
        bf16x8 vf8 = *(const bf16x8*)(Vb + (ch * 16 + l15) * 128 + ((half * 64 + lg * 16) ^ swz));
        oacc[ch] = __builtin_amdgcn_mfma_f32_16x16x32_bf16(pf, vf8, oacc[ch], 0, 0, 0);
      }
      __builtin_amdgcn_s_setprio(0);
    }
    __syncthreads();   // drains prefetch (vmcnt) + publishes next buffer
  }

  // single end-of-kernel l reduction: lanes {l15, l15+16, l15+32, l15+48} hold partials
  l_run += __shfl_xor(l_run, 16);
  l_run += __shfl_xor(l_run, 32);
  float li[4];
#pragma unroll
  for (int r = 0; r < 4; r++) li[r] = 1.f / __shfl(l_run, lg * 4 + r);
#pragma unroll
  for (int ch = 0; ch < 8; ch++)
#pragma unroll
    for (int r = 0; r < 4; r++)
      ao[(size_t)(q0 + lg * 4 + r) * DMODEL + head * HDIM + ch * 16 + l15] =
          f2bf(oacc[ch][r] * li[r]);
}

// ---------------- launch ----------------
extern "C" void kernel_launch(void* const* d_in, const int* in_sizes, int n_in,
                              void* d_out, int out_size, void* d_ws, size_t ws_size,
                              hipStream_t stream)
{
  const float* x    = (const float*)d_in[0];
  const float* Wq   = (const float*)d_in[1];
  const float* bq   = (const float*)d_in[2];
  const float* Wk   = (const float*)d_in[3];
  const float* bk   = (const float*)d_in[4];
  const float* Wv   = (const float*)d_in[5];
  const float* bv   = (const float*)d_in[6];
  const float* Wo   = (const float*)d_in[7];
  const float* bo   = (const float*)d_in[8];
  const float* gq   = (const float*)d_in[9];
  const float* gk   = (const float*)d_in[10];
  const float* fcos = (const float*)d_in[11];
  const float* fsin = (const float*)d_in[12];
  float* out = (float*)d_out;

  char* ws = (char*)d_ws;
  size_t off = 0;
  auto alloc = [&](size_t bytes){
    void* p = ws + off;
    off += (bytes + 255) & ~(size_t)255;
    return p;
  };
  const size_t SD = (size_t)SEQ * DMODEL;
  const size_t WW = (size_t)DMODEL * DMODEL;
  u16*   xb  = (u16*)  alloc(SD * 2);
  u16*   wqb = (u16*)  alloc(WW * 2);
  u16*   wkb = (u16*)  alloc(WW * 2);
  u16*   wvb = (u16*)  alloc(WW * 2);
  u16*   wob = (u16*)  alloc(WW * 2);
  float* qf  = (float*)alloc(SD * 4);
  float* kf  = (float*)alloc(SD * 4);
  float* vf  = (float*)alloc(SD * 4);
  u16*   rq  = (u16*)  alloc(SD * 2);
  u16*   rk  = (u16*)  alloc(SD * 2);
  u16*   vt  = (u16*)  alloc(SD * 2);
  u16*   ao  = (u16*)  alloc(SD * 2);

  int nx4 = (int)(SD / 4), nw4 = (int)(WW / 4);
  cvt4_kernel<<<(nx4 + 255) / 256, 256, 0, stream>>>(x,  xb,  nx4);
  cvt4_kernel<<<(nw4 + 255) / 256, 256, 0, stream>>>(Wq, wqb, nw4);
  cvt4_kernel<<<(nw4 + 255) / 256, 256, 0, stream>>>(Wk, wkb, nw4);
  cvt4_kernel<<<(nw4 + 255) / 256, 256, 0, stream>>>(Wv, wvb, nw4);
  cvt4_kernel<<<(nw4 + 255) / 256, 256, 0, stream>>>(Wo, wob, nw4);

  gemm_qkv<<<dim3(SEQ / 128, 36), 256, 0, stream>>>(xb, wqb, wkb, wvb, bq, bk, bv, qf, kf, vf);
  rmsrope_kernel<<<SEQ, 256, 0, stream>>>(qf, kf, gq, gk, fcos, fsin, rq, rk);
  transpose_v<<<dim3(DMODEL / 32, SEQ / 32), 256, 0, stream>>>(vf, vt);
  attn_kernel<<<dim3(SEQ / 64, NHEAD), 256, 0, stream>>>(rq, rk, vt, ao);
  gemm_o<<<dim3(SEQ / 128, DMODEL / 128), 256, 0, stream>>>(ao, wob, bo, out);
}

// Round 4
// 321.701 us; speedup vs baseline: 2.1039x; 1.0546x over previous
//
#include <hip/hip_runtime.h>
#include <stdint.h>

typedef unsigned short u16;
typedef __attribute__((ext_vector_type(8))) short bf16x8;
typedef __attribute__((ext_vector_type(4))) short bf16x4;
typedef __attribute__((ext_vector_type(4))) float f32x4;

constexpr int DMODEL = 1536;
constexpr int SEQ    = 3072;
constexpr int NHEAD  = 12;
constexpr int HDIM   = 128;

__device__ __forceinline__ u16 f2bf(float f){
  union { float f; unsigned u; } v; v.f = f;
  return (u16)((v.u + 0x7fffu + ((v.u >> 16) & 1u)) >> 16);
}

// ---------------- single fused f32 -> bf16 convert (x, Wq, Wk, Wv, Wo) ----------------
__global__ __launch_bounds__(256) void cvt_all(
    const float* __restrict__ x,  const float* __restrict__ wq,
    const float* __restrict__ wk, const float* __restrict__ wv, const float* __restrict__ wo,
    u16* __restrict__ xb, u16* __restrict__ wqb, u16* __restrict__ wkb,
    u16* __restrict__ wvb, u16* __restrict__ wob)
{
  const int NX = (SEQ * DMODEL) / 4;      // 1,179,648 (multiple of 256)
  const int NW = (DMODEL * DMODEL) / 4;   //   589,824 (multiple of 256)
  int i = blockIdx.x * 256 + threadIdx.x;
  const float* src; u16* dst; int off;
  if      (i < NX)          { src = x;  dst = xb;  off = i; }
  else if (i < NX + NW)     { src = wq; dst = wqb; off = i - NX; }
  else if (i < NX + 2 * NW) { src = wk; dst = wkb; off = i - NX - NW; }
  else if (i < NX + 3 * NW) { src = wv; dst = wvb; off = i - NX - 2 * NW; }
  else                      { src = wo; dst = wob; off = i - NX - 3 * NW; }
  float4 f = ((const float4*)src)[off];
  ushort4 o;
  o.x = f2bf(f.x); o.y = f2bf(f.y); o.z = f2bf(f.z); o.w = f2bf(f.w);
  ((ushort4*)dst)[off] = o;
}

// ---------------- GEMM core: 2-phase pipelined, dbuf LDS ----------------
__device__ __forceinline__ void gload16(const u16* g, u16* l){
  __builtin_amdgcn_global_load_lds((const __attribute__((address_space(1))) void*)g,
                                   (__attribute__((address_space(3))) void*)l, 16, 0, 0);
}

// C[128x128] = A[128xK] * W[128xK]^T + bias. If vfuse: write bf16 transposed+permuted
// into VT[d][SEQ] (32-token groups permuted by p(w)=[w3 w2 w4 w1 w0]) instead of f32 C.
__device__ __forceinline__ void gemm_core(const u16* __restrict__ A, const u16* __restrict__ W,
    const float* __restrict__ bias, float* __restrict__ C, u16* __restrict__ VT,
    int m0, int n0, bool vfuse, u16* As, u16* Bs)
{
  const int tid  = threadIdx.x;
  const int lane = tid & 63;
  const int wv   = tid >> 6;          // 0..3
  const int wm   = wv & 1, wn = wv >> 1;
  const int l15  = lane & 15, lg = lane >> 4;

  f32x4 acc[4][4];
#pragma unroll
  for (int i = 0; i < 4; i++)
#pragma unroll
    for (int j = 0; j < 4; j++){ f32x4 z = {0.f,0.f,0.f,0.f}; acc[i][j] = z; }

  const int r0 = wv * 16 + (lane >> 2);
  const int r1 = (wv + 4) * 16 + (lane >> 2);
  const int cc = (lane & 3) * 8;
  const u16* Ab = A + (size_t)m0 * DMODEL;
  const u16* Wb = W + (size_t)n0 * DMODEL;

  auto stageg = [&](int b, int k0){
    gload16(Ab + (size_t)r0 * DMODEL + k0 + cc, As + b * 4096 + wv * 512);
    gload16(Ab + (size_t)r1 * DMODEL + k0 + cc, As + b * 4096 + (wv + 4) * 512);
    gload16(Wb + (size_t)r0 * DMODEL + k0 + cc, Bs + b * 4096 + wv * 512);
    gload16(Wb + (size_t)r1 * DMODEL + k0 + cc, Bs + b * 4096 + (wv + 4) * 512);
  };

  stageg(0, 0);
  __syncthreads();

  for (int k0 = 0; k0 < DMODEL; k0 += 32){
    int b = (k0 >> 5) & 1;
    if (k0 + 32 < DMODEL) stageg(b ^ 1, k0 + 32);   // prefetch next K-tile

    const u16* Ar = As + b * 4096;
    const u16* Br = Bs + b * 4096;
    bf16x8 af[4], bfr[4];
#pragma unroll
    for (int mi = 0; mi < 4; mi++)
      af[mi]  = *(const bf16x8*)(Ar + (wm * 64 + mi * 16 + l15) * 32 + lg * 8);
#pragma unroll
    for (int ni = 0; ni < 4; ni++)
      bfr[ni] = *(const bf16x8*)(Br + (wn * 64 + ni * 16 + l15) * 32 + lg * 8);
#pragma unroll
    for (int mi = 0; mi < 4; mi++)
#pragma unroll
      for (int ni = 0; ni < 4; ni++)
        acc[mi][ni] = __builtin_amdgcn_mfma_f32_16x16x32_bf16(af[mi], bfr[ni], acc[mi][ni], 0, 0, 0);
    __syncthreads();   // drains own prefetch vmcnt + publishes next buffer
  }

  if (!vfuse){
#pragma unroll
    for (int mi = 0; mi < 4; mi++){
      int row = m0 + wm * 64 + mi * 16 + (lg << 2);
#pragma unroll
      for (int ni = 0; ni < 4; ni++){
        int col = n0 + wn * 64 + ni * 16 + l15;
        float bvv = bias[col];
#pragma unroll
        for (int r = 0; r < 4; r++)
          C[(size_t)(row + r) * DMODEL + col] = acc[mi][ni][r] + bvv;
      }
    }
  } else {
    // transposed + permuted bf16 write into VT[d][SEQ]
#pragma unroll
    for (int mi = 0; mi < 4; mi++){
      int gbase = m0 + wm * 64 + (mi >> 1) * 32 + lg * 8 + (mi & 1) * 4;
#pragma unroll
      for (int ni = 0; ni < 4; ni++){
        int d = n0 + wn * 64 + ni * 16 + l15;
        float bvv = bias[d];
        ushort4 o;
        o.x = f2bf(acc[mi][ni][0] + bvv);
        o.y = f2bf(acc[mi][ni][1] + bvv);
        o.z = f2bf(acc[mi][ni][2] + bvv);
        o.w = f2bf(acc[mi][ni][3] + bvv);
        *(ushort4*)(VT + (size_t)d * SEQ + gbase) = o;
      }
    }
  }
}

__global__ __launch_bounds__(256) void gemm_qkv(const u16* __restrict__ xb,
    const u16* __restrict__ wqb, const u16* __restrict__ wkb, const u16* __restrict__ wvb,
    const float* __restrict__ bq, const float* __restrict__ bk, const float* __restrict__ bv,
    float* __restrict__ qf, float* __restrict__ kf, u16* __restrict__ vt)
{
  __shared__ u16 As[2 * 4096], Bs[2 * 4096];
  int mt = blockIdx.x, nt = blockIdx.y;           // nt in [0,36)
  int sel = nt / 12, ntl = nt % 12;
  const u16* W = sel == 0 ? wqb : (sel == 1 ? wkb : wvb);
  const float* bias = sel == 0 ? bq : (sel == 1 ? bk : bv);
  float* C = sel == 0 ? qf : kf;
  gemm_core(xb, W, bias, C, vt, mt * 128, ntl * 128, sel == 2, As, Bs);
}

__global__ __launch_bounds__(256) void gemm_o(const u16* __restrict__ ab,
    const u16* __restrict__ wob, const float* __restrict__ bo, float* __restrict__ out)
{
  __shared__ u16 As[2 * 4096], Bs[2 * 4096];
  gemm_core(ab, wob, bo, out, nullptr, blockIdx.x * 128, blockIdx.y * 128, false, As, Bs);
}

// ---------------- fused RMSNorm + RoPE: one wave per (token, q/k) row ----------------
__global__ __launch_bounds__(256) void rmsrope_kernel(
    const float* __restrict__ qin, const float* __restrict__ kin,
    const float* __restrict__ gq, const float* __restrict__ gk,
    const float* __restrict__ fcos, const float* __restrict__ fsin,
    u16* __restrict__ rq, u16* __restrict__ rk)
{
  int gw   = (blockIdx.x * 256 + threadIdx.x) >> 6;   // 0..6143
  int lane = threadIdx.x & 63;
  int s    = gw >> 1;
  int pass = gw & 1;
  const float* in = pass ? kin : qin;
  const float* g  = pass ? gk  : gq;
  u16* outp       = pass ? rk  : rq;

  const float* row = in + (size_t)s * DMODEL + lane * 24;
  float v[24];
#pragma unroll
  for (int j = 0; j < 6; j++) *(float4*)(v + 4 * j) = ((const float4*)row)[j];

  float ss = 0.f;
#pragma unroll
  for (int j = 0; j < 24; j++) ss += v[j] * v[j];
#pragma unroll
  for (int m = 1; m < 64; m <<= 1) ss += __shfl_xor(ss, m);
  float scale = rsqrtf(ss * (1.0f / (float)DMODEL) + 1e-6f);

  float gv[24];
  const float* gp = g + lane * 24;
#pragma unroll
  for (int j = 0; j < 6; j++) *(float4*)(gv + 4 * j) = ((const float4*)gp)[j];

  int fi = s >> 8, hi2 = (s >> 4) & 15, wi = s & 15;
  u16 o[24];
#pragma unroll
  for (int jp = 0; jp < 12; jp++){
    int i  = lane * 12 + jp;     // global pair index 0..767
    int pi = i & 63;             // pair within head
    int idx = pi < 22 ? fi : (pi < 43 ? hi2 : wi);
    float cv = fcos[idx * 64 + pi];
    float sv = fsin[idx * 64 + pi];
    float xr = v[2 * jp]     * scale * gv[2 * jp];
    float xi = v[2 * jp + 1] * scale * gv[2 * jp + 1];
    o[2 * jp]     = f2bf(xr * cv - xi * sv);
    o[2 * jp + 1] = f2bf(xr * sv + xi * cv);
  }
  u16* op = outp + (size_t)s * DMODEL + lane * 24;
#pragma unroll
  for (int j = 0; j < 3; j++) *(bf16x8*)(op + 8 * j) = *(bf16x8*)(o + 8 * j);
}

// ---------------- attention v4: split-K units, fixed-max softmax, f32 partials ----------------
// Unit = (head, 64-query block, key-subrange of 12 or 14 tiles of 64 keys).
// 84 units/head x 12 heads = 1008 blocks, perfectly balanced (12-14 tiles each).
// Fixed-max softmax (scores bounded ~11.5) -> partials are pure sums; reduce combines.
__global__ __launch_bounds__(256, 2) void attn_kernel(const u16* __restrict__ rq,
    const u16* __restrict__ rk, const u16* __restrict__ vt,
    float* __restrict__ pO, float* __restrict__ pl)
{
  __shared__ u16 Ks[2][8192];
  __shared__ u16 Vs[2][8192];

  const int tid  = threadIdx.x;
  const int lane = tid & 63;
  const int wv   = tid >> 6;
  const int head = blockIdx.y;
  const int bid  = blockIdx.x;               // 0..83 (longest units first)
  int qb, blk, sub;
  if      (bid < 24){ qb = 3; blk = bid >> 1;        sub = bid & 1; }
  else if (bid < 48){ qb = 2; blk = (bid - 24) >> 1; sub = bid & 1; }
  else if (bid < 72){ qb = 1; blk = (bid - 48) >> 1; sub = bid & 1; }
  else              { qb = 0; blk = bid - 72;        sub = 0; }
  const int qblk = qb * 12 + blk;            // 0..47
  const int q0   = qblk * 64 + wv * 16;
  const int l15  = lane & 15, lg = lane >> 4;
  const int swz  = (l15 & 7) << 4;
  const float sc = 0.08838834764831845f;     // 1/sqrt(128)

  int r1s = 0, r1e = 0, r0e = 0;
  if      (qb == 0){ r0e = 768; }
  else if (qb == 1){ r0e = 1536; }
  else if (qb == 2){ r0e = 256; r1s = 768;  r1e = 2304; }
  else             { r0e = 256; r1s = 1536; r1e = 3072; }
  const int nt0 = r0e >> 6;
  const int nt  = nt0 + ((r1e - r1s) >> 6);
  const int hl  = (qb == 0) ? nt : (nt >> 1);
  const int ts  = sub * hl, te = ts + hl;

  const char* rkB = (const char*)rk;
  const char* vtB = (const char*)vt;
  auto k0_of = [&](int t){ return t < nt0 ? t * 64 : (r1s + (t - nt0) * 64); };

  auto stage = [&](int buf, int k0){
    char* Kd = (char*)Ks[buf];
    char* Vd = (char*)Vs[buf];
#pragma unroll
    for (int c = 0; c < 4; c++){
      int o = c * 4096 + wv * 1024 + lane * 16;
      int row = o >> 8, colb = o & 255;
      gload16((const u16*)(rkB + (size_t)(k0 + row) * (DMODEL * 2) + head * (HDIM * 2)
                               + (colb ^ ((row & 7) << 4))),
              (u16*)(Kd + c * 4096 + wv * 1024));
    }
#pragma unroll
    for (int c = 0; c < 4; c++){
      int o = c * 4096 + wv * 1024 + lane * 16;
      int row = o >> 7, colb = o & 127;
      gload16((const u16*)(vtB + (size_t)(head * HDIM + row) * (SEQ * 2) + (size_t)k0 * 2
                               + (colb ^ ((row & 7) << 4))),
              (u16*)(Vd + c * 4096 + wv * 1024));
    }
  };

  bf16x8 qfr[4];
  const u16* qbase = rq + (size_t)(q0 + l15) * DMODEL + head * HDIM + lg * 8;
#pragma unroll
  for (int c = 0; c < 4; c++) qfr[c] = *(const bf16x8*)(qbase + c * 32);

  f32x4 oacc[8];
#pragma unroll
  for (int i = 0; i < 8; i++){ f32x4 z = {0.f,0.f,0.f,0.f}; oacc[i] = z; }
  float l_run = 0.f;

  stage(0, k0_of(ts));
  __syncthreads();

  for (int t = ts; t < te; t++){
    int buf = (t - ts) & 1;
    if (t + 1 < te) stage(buf ^ 1, k0_of(t + 1));

    const char* Kb = (const char*)Ks[buf];
    const char* Vb = (const char*)Vs[buf];
#pragma unroll
    for (int half = 0; half < 2; half++){
      const int kt = half * 32;
      const char* kr0 = Kb + (kt + l15) * 256;
      const char* kr1 = kr0 + 16 * 256;
      bf16x8 kf0[4], kf1[4];
#pragma unroll
      for (int c = 0; c < 4; c++){
        kf0[c] = *(const bf16x8*)(kr0 + ((lg * 16 + c * 64) ^ swz));
        kf1[c] = *(const bf16x8*)(kr1 + ((lg * 16 + c * 64) ^ swz));
      }
      f32x4 s0 = {0.f,0.f,0.f,0.f}, s1 = {0.f,0.f,0.f,0.f};
      __builtin_amdgcn_s_setprio(1);
#pragma unroll
      for (int c = 0; c < 4; c++){
        s0 = __builtin_amdgcn_mfma_f32_16x16x32_bf16(kf0[c], qfr[c], s0, 0, 0, 0);
        s1 = __builtin_amdgcn_mfma_f32_16x16x32_bf16(kf1[c], qfr[c], s1, 0, 0, 0);
      }
      __builtin_amdgcn_s_setprio(0);

      bf16x8 pf;
      float lsum = 0.f;
#pragma unroll
      for (int r = 0; r < 4; r++){
        float e0 = __expf(fmaf(s0[r], sc, -12.f));
        float e1 = __expf(fmaf(s1[r], sc, -12.f));
        lsum += e0 + e1;
        pf[r]     = (short)f2bf(e0);
        pf[r + 4] = (short)f2bf(e1);
      }
      l_run += lsum;

      __builtin_amdgcn_s_setprio(1);
#pragma unroll
      for (int ch = 0; ch < 8; ch++){
        bf16x8 vf8 = *(const bf16x8*)(Vb + (ch * 16 + l15) * 128 + ((half * 64 + lg * 16) ^ swz));
        oacc[ch] = __builtin_amdgcn_mfma_f32_16x16x32_bf16(pf, vf8, oacc[ch], 0, 0, 0);
      }
      __builtin_amdgcn_s_setprio(0);
    }
    __syncthreads();
  }

  // write partials: l for query l15 (after cross-lg reduce), O at [q_local][d]
  const size_t punit = (size_t)(head * 84 + bid);
  l_run += __shfl_xor(l_run, 16);
  l_run += __shfl_xor(l_run, 32);
  if (lg == 0) pl[punit * 64 + wv * 16 + l15] = l_run;

  float* po = pO + punit * 8192;
#pragma unroll
  for (int ch = 0; ch < 8; ch++)
#pragma unroll
    for (int r = 0; r < 4; r++)
      po[(wv * 16 + lg * 4 + r) * 128 + ch * 16 + l15] = oacc[ch][r];
}

// ---------------- attn reduce: combine split-K partials, normalize, write bf16 ----------------
__global__ __launch_bounds__(256) void attn_reduce(const float* __restrict__ pO,
    const float* __restrict__ pl, u16* __restrict__ ao)
{
  const int qblk = blockIdx.x;   // 0..47
  const int head = blockIdx.y;
  const int qb = qblk / 12, blk = qblk % 12;
  int b0, nu;
  if      (qb == 0){ b0 = 72 + blk;     nu = 1; }
  else if (qb == 1){ b0 = 48 + 2 * blk; nu = 2; }
  else if (qb == 2){ b0 = 24 + 2 * blk; nu = 2; }
  else             { b0 = 2 * blk;      nu = 2; }
  const size_t u0 = (size_t)(head * 84 + b0);
  const float* O0 = pO + u0 * 8192;
  const float* L0 = pl + u0 * 64;

  __shared__ float ls[64];
  int t = threadIdx.x;
  if (t < 64) ls[t] = L0[t] + (nu == 2 ? L0[64 + t] : 0.f);
  __syncthreads();

  int q = t >> 2, dc = (t & 3) * 32;
  float inv = 1.f / ls[q];
  const float* a0 = O0 + q * 128 + dc;
  const float* a1 = a0 + 8192;
  u16 buf[32];
#pragma unroll
  for (int j = 0; j < 32; j += 4){
    float4 xv = *(const float4*)(a0 + j);
    if (nu == 2){
      float4 y = *(const float4*)(a1 + j);
      xv.x += y.x; xv.y += y.y; xv.z += y.z; xv.w += y.w;
    }
    buf[j]     = f2bf(xv.x * inv);
    buf[j + 1] = f2bf(xv.y * inv);
    buf[j + 2] = f2bf(xv.z * inv);
    buf[j + 3] = f2bf(xv.w * inv);
  }
  u16* op = ao + (size_t)(qblk * 64 + q) * DMODEL + head * HDIM + dc;
#pragma unroll
  for (int j = 0; j < 32; j += 8) *(bf16x8*)(op + j) = *(bf16x8*)(buf + j);
}

// ---------------- launch ----------------
extern "C" void kernel_launch(void* const* d_in, const int* in_sizes, int n_in,
                              void* d_out, int out_size, void* d_ws, size_t ws_size,
                              hipStream_t stream)
{
  const float* x    = (const float*)d_in[0];
  const float* Wq   = (const float*)d_in[1];
  const float* bq   = (const float*)d_in[2];
  const float* Wk   = (const float*)d_in[3];
  const float* bk   = (const float*)d_in[4];
  const float* Wv   = (const float*)d_in[5];
  const float* bv   = (const float*)d_in[6];
  const float* Wo   = (const float*)d_in[7];
  const float* bo   = (const float*)d_in[8];
  const float* gq   = (const float*)d_in[9];
  const float* gk   = (const float*)d_in[10];
  const float* fcos = (const float*)d_in[11];
  const float* fsin = (const float*)d_in[12];
  float* out = (float*)d_out;

  char* ws = (char*)d_ws;
  size_t off = 0;
  auto alloc = [&](size_t bytes){
    void* p = ws + off;
    off += (bytes + 255) & ~(size_t)255;
    return p;
  };
  const size_t SD = (size_t)SEQ * DMODEL;
  const size_t WW = (size_t)DMODEL * DMODEL;
  u16*   xb  = (u16*)  alloc(SD * 2);
  u16*   wqb = (u16*)  alloc(WW * 2);
  u16*   wkb = (u16*)  alloc(WW * 2);
  u16*   wvb = (u16*)  alloc(WW * 2);
  u16*   wob = (u16*)  alloc(WW * 2);
  float* qf  = (float*)alloc(SD * 4);
  float* kf  = (float*)alloc(SD * 4);
  u16*   rq  = (u16*)  alloc(SD * 2);
  u16*   rk  = (u16*)  alloc(SD * 2);
  u16*   vt  = (u16*)  alloc(SD * 2);
  u16*   ao  = (u16*)  alloc(SD * 2);
  float* pl  = (float*)alloc((size_t)1008 * 64 * 4);
  // partial O aliases the qf/kf region (dead after rmsrope): 1008*8192*4 = 33MB < 37.7MB
  float* pO  = qf;

  const int NX = (SEQ * DMODEL) / 4, NW = (DMODEL * DMODEL) / 4;
  cvt_all<<<(NX + 4 * NW) / 256, 256, 0, stream>>>(x, Wq, Wk, Wv, Wo, xb, wqb, wkb, wvb, wob);
  gemm_qkv<<<dim3(SEQ / 128, 36), 256, 0, stream>>>(xb, wqb, wkb, wvb, bq, bk, bv, qf, kf, vt);
  rmsrope_kernel<<<(SEQ * 2) / 4, 256, 0, stream>>>(qf, kf, gq, gk, fcos, fsin, rq, rk);
  attn_kernel<<<dim3(84, NHEAD), 256, 0, stream>>>(rq, rk, vt, pO, pl);
  attn_reduce<<<dim3(48, NHEAD), 256, 0, stream>>>(pO, pl, ao);
  gemm_o<<<dim3(SEQ / 128, DMODEL / 128), 256, 0, stream>>>(ao, wob, bo, out);
}

// Round 5
// 289.876 us; speedup vs baseline: 2.3349x; 1.1098x over previous
//
#include <hip/hip_runtime.h>
#include <stdint.h>

typedef unsigned short u16;
typedef __attribute__((ext_vector_type(8))) short bf16x8;
typedef __attribute__((ext_vector_type(4))) short bf16x4;
typedef __attribute__((ext_vector_type(4))) float f32x4;

constexpr int DMODEL = 1536;
constexpr int SEQ    = 3072;
constexpr int NHEAD  = 12;
constexpr int HDIM   = 128;

__device__ __forceinline__ u16 f2bf(float f){
  union { float f; unsigned u; } v; v.f = f;
  return (u16)((v.u + 0x7fffu + ((v.u >> 16) & 1u)) >> 16);
}

// ---------------- single fused f32 -> bf16 convert (x, Wq, Wk, Wv, Wo) ----------------
__global__ __launch_bounds__(256) void cvt_all(
    const float* __restrict__ x,  const float* __restrict__ wq,
    const float* __restrict__ wk, const float* __restrict__ wv, const float* __restrict__ wo,
    u16* __restrict__ xb, u16* __restrict__ wqb, u16* __restrict__ wkb,
    u16* __restrict__ wvb, u16* __restrict__ wob)
{
  const int NX = (SEQ * DMODEL) / 4;
  const int NW = (DMODEL * DMODEL) / 4;
  int i = blockIdx.x * 256 + threadIdx.x;
  const float* src; u16* dst; int off;
  if      (i < NX)          { src = x;  dst = xb;  off = i; }
  else if (i < NX + NW)     { src = wq; dst = wqb; off = i - NX; }
  else if (i < NX + 2 * NW) { src = wk; dst = wkb; off = i - NX - NW; }
  else if (i < NX + 3 * NW) { src = wv; dst = wvb; off = i - NX - 2 * NW; }
  else                      { src = wo; dst = wob; off = i - NX - 3 * NW; }
  float4 f = ((const float4*)src)[off];
  ushort4 o;
  o.x = f2bf(f.x); o.y = f2bf(f.y); o.z = f2bf(f.z); o.w = f2bf(f.w);
  ((ushort4*)dst)[off] = o;
}

__device__ __forceinline__ void gload16(const u16* g, u16* l){
  __builtin_amdgcn_global_load_lds((const __attribute__((address_space(1))) void*)g,
                                   (__attribute__((address_space(3))) void*)l, 16, 0, 0);
}

// ================= 8-phase 256x256 GEMM for QKV (BK=64, 8 waves, 128KiB LDS) =================
// C[256x256] = A[256xK] * W[256xK]^T (+bias). sel 0/1 -> f32 qf/kf; sel 2 -> bf16
// transposed+permuted V write into vt[d][SEQ].
// Iteration t: compute buf[t&1]; stage K-tile t+1 -> buf[(t+1)&1] (A in phase 0, B in
// phase 1); single vmcnt(0) at end of phase 3 (stage->wait slack ~2-3 phases).
__global__ __launch_bounds__(512, 2) void gemm_qkv256(const u16* __restrict__ xb,
    const u16* __restrict__ wqb, const u16* __restrict__ wkb, const u16* __restrict__ wvb,
    const float* __restrict__ bq, const float* __restrict__ bk, const float* __restrict__ bv,
    float* __restrict__ qf, float* __restrict__ kf, u16* __restrict__ vt)
{
  __shared__ u16 lds[2][2][16384];   // [buf][A/B][256 rows x 64 k]

  const int tid  = threadIdx.x;
  const int lane = tid & 63;
  const int wid  = tid >> 6;       // 0..7
  const int wm   = wid >> 2;       // 0..1
  const int wn   = wid & 3;        // 0..3
  const int l15  = lane & 15, lg = lane >> 4;
  const int swz  = (l15 & 7) << 4;

  const int bid  = blockIdx.x;                 // 216 = 8 * 27
  const int sbid = (bid & 7) * 27 + (bid >> 3);
  const int mt   = sbid / 18, nt = sbid % 18;
  const int sel  = nt / 6, ntl = nt % 6;
  const u16* W = sel == 0 ? wqb : (sel == 1 ? wkb : wvb);
  const float* bias = sel == 0 ? bq : (sel == 1 ? bk : bv);
  const int m0 = mt * 256, n0 = ntl * 256;

  const char* Ag = (const char*)(xb + (size_t)m0 * DMODEL);
  const char* Bg = (const char*)(W  + (size_t)n0 * DMODEL);

  auto stage_op = [&](int buf, int op, const char* G, int kt){
#pragma unroll
    for (int c = 0; c < 4; c++){
      int ob  = c * 8192 + wid * 1024 + lane * 16;   // this lane's dest byte
      int row = ob >> 7, colb = ob & 127;
      gload16((const u16*)(G + (size_t)row * (DMODEL * 2) + (size_t)kt * 128
                             + (colb ^ ((row & 7) << 4))),
              (u16*)((char*)&lds[buf][op][0] + c * 8192 + wid * 1024));
    }
  };

  f32x4 acc[8][4];
#pragma unroll
  for (int i = 0; i < 8; i++)
#pragma unroll
    for (int j = 0; j < 4; j++){ f32x4 z = {0.f,0.f,0.f,0.f}; acc[i][j] = z; }

  const int NK = DMODEL / 64;   // 24

  stage_op(0, 0, Ag, 0);
  stage_op(0, 1, Bg, 0);
  asm volatile("s_waitcnt vmcnt(0)" ::: "memory");
  __builtin_amdgcn_sched_barrier(0);
  __builtin_amdgcn_s_barrier();
  __builtin_amdgcn_sched_barrier(0);

#pragma unroll 1
  for (int t = 0; t < NK; t++){
    const int b = t & 1;
    const char* Abase = (const char*)&lds[b][0][0];
    const char* Bbase = (const char*)&lds[b][1][0];
    bf16x8 bfr[4][2], afr[2][2];

    // ---------- phase 0: read all B-frags + A mi{0,1}; stage A(t+1) ----------
#pragma unroll
    for (int ni = 0; ni < 4; ni++){
      int rb = wn * 64 + ni * 16 + l15;
#pragma unroll
      for (int ks = 0; ks < 2; ks++)
        bfr[ni][ks] = *(const bf16x8*)(Bbase + rb * 128 + ((ks * 64 + lg * 16) ^ swz));
    }
#pragma unroll
    for (int i = 0; i < 2; i++){
      int ra = wm * 128 + i * 16 + l15;
#pragma unroll
      for (int ks = 0; ks < 2; ks++)
        afr[i][ks] = *(const bf16x8*)(Abase + ra * 128 + ((ks * 64 + lg * 16) ^ swz));
    }
    if (t + 1 < NK) stage_op(b ^ 1, 0, Ag, t + 1);
    __builtin_amdgcn_sched_barrier(0);
    __builtin_amdgcn_s_barrier();
    __builtin_amdgcn_sched_barrier(0);
    __builtin_amdgcn_s_setprio(1);
#pragma unroll
    for (int i = 0; i < 2; i++)
#pragma unroll
      for (int ni = 0; ni < 4; ni++)
#pragma unroll
        for (int ks = 0; ks < 2; ks++)
          acc[i][ni] = __builtin_amdgcn_mfma_f32_16x16x32_bf16(afr[i][ks], bfr[ni][ks], acc[i][ni], 0, 0, 0);
    __builtin_amdgcn_s_setprio(0);
    __builtin_amdgcn_sched_barrier(0);
    __builtin_amdgcn_s_barrier();
    __builtin_amdgcn_sched_barrier(0);

    // ---------- phases 1..3: read A mi{2qd,2qd+1}; stage B(t+1) at qd==1 ----------
#pragma unroll
    for (int qd = 1; qd < 4; qd++){
#pragma unroll
      for (int i = 0; i < 2; i++){
        int ra = wm * 128 + (qd * 2 + i) * 16 + l15;
#pragma unroll
        for (int ks = 0; ks < 2; ks++)
          afr[i][ks] = *(const bf16x8*)(Abase + ra * 128 + ((ks * 64 + lg * 16) ^ swz));
      }
      if (qd == 1 && t + 1 < NK) stage_op(b ^ 1, 1, Bg, t + 1);
      __builtin_amdgcn_sched_barrier(0);
      __builtin_amdgcn_s_barrier();
      __builtin_amdgcn_sched_barrier(0);
      __builtin_amdgcn_s_setprio(1);
#pragma unroll
      for (int i = 0; i < 2; i++)
#pragma unroll
        for (int ni = 0; ni < 4; ni++)
#pragma unroll
          for (int ks = 0; ks < 2; ks++)
            acc[qd * 2 + i][ni] = __builtin_amdgcn_mfma_f32_16x16x32_bf16(afr[i][ks], bfr[ni][ks], acc[qd * 2 + i][ni], 0, 0, 0);
      __builtin_amdgcn_s_setprio(0);
      if (qd == 3) asm volatile("s_waitcnt vmcnt(0)" ::: "memory");  // drain K-tile t+1 stages
      __builtin_amdgcn_sched_barrier(0);
      __builtin_amdgcn_s_barrier();
      __builtin_amdgcn_sched_barrier(0);
    }
  }

  if (sel != 2){
    float* C = sel == 0 ? qf : kf;
#pragma unroll
    for (int mi = 0; mi < 8; mi++){
      int row = m0 + wm * 128 + mi * 16 + lg * 4;
#pragma unroll
      for (int ni = 0; ni < 4; ni++){
        int col = n0 + wn * 64 + ni * 16 + l15;
        float bvv = bias[col];
#pragma unroll
        for (int r = 0; r < 4; r++)
          C[(size_t)(row + r) * DMODEL + col] = acc[mi][ni][r] + bvv;
      }
    }
  } else {
    // transposed + key-permuted bf16 write into vt[d][SEQ]
#pragma unroll
    for (int mi = 0; mi < 8; mi++){
      int gbase = m0 + wm * 128 + (mi >> 1) * 32 + lg * 8 + (mi & 1) * 4;
#pragma unroll
      for (int ni = 0; ni < 4; ni++){
        int d = n0 + wn * 64 + ni * 16 + l15;
        float bvv = bias[d];
        ushort4 o;
        o.x = f2bf(acc[mi][ni][0] + bvv);
        o.y = f2bf(acc[mi][ni][1] + bvv);
        o.z = f2bf(acc[mi][ni][2] + bvv);
        o.w = f2bf(acc[mi][ni][3] + bvv);
        *(ushort4*)(vt + (size_t)d * SEQ + gbase) = o;
      }
    }
  }
}

// ---------------- GEMM core (128^2, 2-phase) -- used by gemm_o ----------------
__device__ __forceinline__ void gemm_core(const u16* __restrict__ A, const u16* __restrict__ W,
    const float* __restrict__ bias, float* __restrict__ C, int m0, int n0,
    u16* As, u16* Bs)
{
  const int tid  = threadIdx.x;
  const int lane = tid & 63;
  const int wv   = tid >> 6;
  const int wm   = wv & 1, wn = wv >> 1;
  const int l15  = lane & 15, lg = lane >> 4;

  f32x4 acc[4][4];
#pragma unroll
  for (int i = 0; i < 4; i++)
#pragma unroll
    for (int j = 0; j < 4; j++){ f32x4 z = {0.f,0.f,0.f,0.f}; acc[i][j] = z; }

  const int r0 = wv * 16 + (lane >> 2);
  const int r1 = (wv + 4) * 16 + (lane >> 2);
  const int cc = (lane & 3) * 8;
  const u16* Ab = A + (size_t)m0 * DMODEL;
  const u16* Wb = W + (size_t)n0 * DMODEL;

  auto stageg = [&](int b, int k0){
    gload16(Ab + (size_t)r0 * DMODEL + k0 + cc, As + b * 4096 + wv * 512);
    gload16(Ab + (size_t)r1 * DMODEL + k0 + cc, As + b * 4096 + (wv + 4) * 512);
    gload16(Wb + (size_t)r0 * DMODEL + k0 + cc, Bs + b * 4096 + wv * 512);
    gload16(Wb + (size_t)r1 * DMODEL + k0 + cc, Bs + b * 4096 + (wv + 4) * 512);
  };

  stageg(0, 0);
  __syncthreads();

  for (int k0 = 0; k0 < DMODEL; k0 += 32){
    int b = (k0 >> 5) & 1;
    if (k0 + 32 < DMODEL) stageg(b ^ 1, k0 + 32);

    const u16* Ar = As + b * 4096;
    const u16* Br = Bs + b * 4096;
    bf16x8 af[4], bfr[4];
#pragma unroll
    for (int mi = 0; mi < 4; mi++)
      af[mi]  = *(const bf16x8*)(Ar + (wm * 64 + mi * 16 + l15) * 32 + lg * 8);
#pragma unroll
    for (int ni = 0; ni < 4; ni++)
      bfr[ni] = *(const bf16x8*)(Br + (wn * 64 + ni * 16 + l15) * 32 + lg * 8);
#pragma unroll
    for (int mi = 0; mi < 4; mi++)
#pragma unroll
      for (int ni = 0; ni < 4; ni++)
        acc[mi][ni] = __builtin_amdgcn_mfma_f32_16x16x32_bf16(af[mi], bfr[ni], acc[mi][ni], 0, 0, 0);
    __syncthreads();
  }

#pragma unroll
  for (int mi = 0; mi < 4; mi++){
    int row = m0 + wm * 64 + mi * 16 + (lg << 2);
#pragma unroll
    for (int ni = 0; ni < 4; ni++){
      int col = n0 + wn * 64 + ni * 16 + l15;
      float bvv = bias[col];
#pragma unroll
      for (int r = 0; r < 4; r++)
        C[(size_t)(row + r) * DMODEL + col] = acc[mi][ni][r] + bvv;
    }
  }
}

__global__ __launch_bounds__(256) void gemm_o(const u16* __restrict__ ab,
    const u16* __restrict__ wob, const float* __restrict__ bo, float* __restrict__ out)
{
  __shared__ u16 As[2 * 4096], Bs[2 * 4096];
  gemm_core(ab, wob, bo, out, blockIdx.x * 128, blockIdx.y * 128, As, Bs);
}

// ---------------- fused RMSNorm + RoPE: one wave per (token, q/k) row ----------------
__global__ __launch_bounds__(256) void rmsrope_kernel(
    const float* __restrict__ qin, const float* __restrict__ kin,
    const float* __restrict__ gq, const float* __restrict__ gk,
    const float* __restrict__ fcos, const float* __restrict__ fsin,
    u16* __restrict__ rq, u16* __restrict__ rk)
{
  int gw   = (blockIdx.x * 256 + threadIdx.x) >> 6;
  int lane = threadIdx.x & 63;
  int s    = gw >> 1;
  int pass = gw & 1;
  const float* in = pass ? kin : qin;
  const float* g  = pass ? gk  : gq;
  u16* outp       = pass ? rk  : rq;

  const float* row = in + (size_t)s * DMODEL + lane * 24;
  float v[24];
#pragma unroll
  for (int j = 0; j < 6; j++) *(float4*)(v + 4 * j) = ((const float4*)row)[j];

  float ss = 0.f;
#pragma unroll
  for (int j = 0; j < 24; j++) ss += v[j] * v[j];
#pragma unroll
  for (int m = 1; m < 64; m <<= 1) ss += __shfl_xor(ss, m);
  float scale = rsqrtf(ss * (1.0f / (float)DMODEL) + 1e-6f);

  float gv[24];
  const float* gp = g + lane * 24;
#pragma unroll
  for (int j = 0; j < 6; j++) *(float4*)(gv + 4 * j) = ((const float4*)gp)[j];

  int fi = s >> 8, hi2 = (s >> 4) & 15, wi = s & 15;
  u16 o[24];
#pragma unroll
  for (int jp = 0; jp < 12; jp++){
    int i  = lane * 12 + jp;
    int pi = i & 63;
    int idx = pi < 22 ? fi : (pi < 43 ? hi2 : wi);
    float cv = fcos[idx * 64 + pi];
    float sv = fsin[idx * 64 + pi];
    float xr = v[2 * jp]     * scale * gv[2 * jp];
    float xi = v[2 * jp + 1] * scale * gv[2 * jp + 1];
    o[2 * jp]     = f2bf(xr * cv - xi * sv);
    o[2 * jp + 1] = f2bf(xr * sv + xi * cv);
  }
  u16* op = outp + (size_t)s * DMODEL + lane * 24;
#pragma unroll
  for (int j = 0; j < 3; j++) *(bf16x8*)(op + 8 * j) = *(bf16x8*)(o + 8 * j);
}

// ---------------- attention: split-K units, fixed-max softmax, f32 partials ----------------
__global__ __launch_bounds__(256, 2) void attn_kernel(const u16* __restrict__ rq,
    const u16* __restrict__ rk, const u16* __restrict__ vt,
    float* __restrict__ pO, float* __restrict__ pl)
{
  __shared__ u16 Ks[2][8192];
  __shared__ u16 Vs[2][8192];

  const int tid  = threadIdx.x;
  const int lane = tid & 63;
  const int wv   = tid >> 6;
  const int head = blockIdx.y;
  const int bid  = blockIdx.x;
  int qb, blk, sub;
  if      (bid < 24){ qb = 3; blk = bid >> 1;        sub = bid & 1; }
  else if (bid < 48){ qb = 2; blk = (bid - 24) >> 1; sub = bid & 1; }
  else if (bid < 72){ qb = 1; blk = (bid - 48) >> 1; sub = bid & 1; }
  else              { qb = 0; blk = bid - 72;        sub = 0; }
  const int qblk = qb * 12 + blk;
  const int q0   = qblk * 64 + wv * 16;
  const int l15  = lane & 15, lg = lane >> 4;
  const int swz  = (l15 & 7) << 4;
  const float sc = 0.08838834764831845f;

  int r1s = 0, r1e = 0, r0e = 0;
  if      (qb == 0){ r0e = 768; }
  else if (qb == 1){ r0e = 1536; }
  else if (qb == 2){ r0e = 256; r1s = 768;  r1e = 2304; }
  else             { r0e = 256; r1s = 1536; r1e = 3072; }
  const int nt0 = r0e >> 6;
  const int nt  = nt0 + ((r1e - r1s) >> 6);
  const int hl  = (qb == 0) ? nt : (nt >> 1);
  const int ts  = sub * hl, te = ts + hl;

  const char* rkB = (const char*)rk;
  const char* vtB = (const char*)vt;
  auto k0_of = [&](int t){ return t < nt0 ? t * 64 : (r1s + (t - nt0) * 64); };

  auto stage = [&](int buf, int k0){
    char* Kd = (char*)Ks[buf];
    char* Vd = (char*)Vs[buf];
#pragma unroll
    for (int c = 0; c < 4; c++){
      int o = c * 4096 + wv * 1024 + lane * 16;
      int row = o >> 8, colb = o & 255;
      gload16((const u16*)(rkB + (size_t)(k0 + row) * (DMODEL * 2) + head * (HDIM * 2)
                               + (colb ^ ((row & 7) << 4))),
              (u16*)(Kd + c * 4096 + wv * 1024));
    }
#pragma unroll
    for (int c = 0; c < 4; c++){
      int o = c * 4096 + wv * 1024 + lane * 16;
      int row = o >> 7, colb = o & 127;
      gload16((const u16*)(vtB + (size_t)(head * HDIM + row) * (SEQ * 2) + (size_t)k0 * 2
                               + (colb ^ ((row & 7) << 4))),
              (u16*)(Vd + c * 4096 + wv * 1024));
    }
  };

  bf16x8 qfr[4];
  const u16* qbase = rq + (size_t)(q0 + l15) * DMODEL + head * HDIM + lg * 8;
#pragma unroll
  for (int c = 0; c < 4; c++) qfr[c] = *(const bf16x8*)(qbase + c * 32);

  f32x4 oacc[8];
#pragma unroll
  for (int i = 0; i < 8; i++){ f32x4 z = {0.f,0.f,0.f,0.f}; oacc[i] = z; }
  float l_run = 0.f;

  stage(0, k0_of(ts));
  __syncthreads();

  for (int t = ts; t < te; t++){
    int buf = (t - ts) & 1;
    if (t + 1 < te) stage(buf ^ 1, k0_of(t + 1));

    const char* Kb = (const char*)Ks[buf];
    const char* Vb = (const char*)Vs[buf];
#pragma unroll
    for (int half = 0; half < 2; half++){
      const int kt = half * 32;
      const char* kr0 = Kb + (kt + l15) * 256;
      const char* kr1 = kr0 + 16 * 256;
      bf16x8 kf0[4], kf1[4];
#pragma unroll
      for (int c = 0; c < 4; c++){
        kf0[c] = *(const bf16x8*)(kr0 + ((lg * 16 + c * 64) ^ swz));
        kf1[c] = *(const bf16x8*)(kr1 + ((lg * 16 + c * 64) ^ swz));
      }
      f32x4 s0 = {0.f,0.f,0.f,0.f}, s1 = {0.f,0.f,0.f,0.f};
      __builtin_amdgcn_s_setprio(1);
#pragma unroll
      for (int c = 0; c < 4; c++){
        s0 = __builtin_amdgcn_mfma_f32_16x16x32_bf16(kf0[c], qfr[c], s0, 0, 0, 0);
        s1 = __builtin_amdgcn_mfma_f32_16x16x32_bf16(kf1[c], qfr[c], s1, 0, 0, 0);
      }
      __builtin_amdgcn_s_setprio(0);

      bf16x8 pf;
      float lsum = 0.f;
#pragma unroll
      for (int r = 0; r < 4; r++){
        float e0 = __expf(fmaf(s0[r], sc, -12.f));
        float e1 = __expf(fmaf(s1[r], sc, -12.f));
        lsum += e0 + e1;
        pf[r]     = (short)f2bf(e0);
        pf[r + 4] = (short)f2bf(e1);
      }
      l_run += lsum;

      __builtin_amdgcn_s_setprio(1);
#pragma unroll
      for (int ch = 0; ch < 8; ch++){
        bf16x8 vf8 = *(const bf16x8*)(Vb + (ch * 16 + l15) * 128 + ((half * 64 + lg * 16) ^ swz));
        oacc[ch] = __builtin_amdgcn_mfma_f32_16x16x32_bf16(pf, vf8, oacc[ch], 0, 0, 0);
      }
      __builtin_amdgcn_s_setprio(0);
    }
    __syncthreads();
  }

  const size_t punit = (size_t)(head * 84 + bid);
  l_run += __shfl_xor(l_run, 16);
  l_run += __shfl_xor(l_run, 32);
  if (lg == 0) pl[punit * 64 + wv * 16 + l15] = l_run;

  float* po = pO + punit * 8192;
#pragma unroll
  for (int ch = 0; ch < 8; ch++)
#pragma unroll
    for (int r = 0; r < 4; r++)
      po[(wv * 16 + lg * 4 + r) * 128 + ch * 16 + l15] = oacc[ch][r];
}

// ---------------- attn reduce ----------------
__global__ __launch_bounds__(256) void attn_reduce(const float* __restrict__ pO,
    const float* __restrict__ pl, u16* __restrict__ ao)
{
  const int qblk = blockIdx.x;
  const int head = blockIdx.y;
  const int qb = qblk / 12, blk = qblk % 12;
  int b0, nu;
  if      (qb == 0){ b0 = 72 + blk;     nu = 1; }
  else if (qb == 1){ b0 = 48 + 2 * blk; nu = 2; }
  else if (qb == 2){ b0 = 24 + 2 * blk; nu = 2; }
  else             { b0 = 2 * blk;      nu = 2; }
  const size_t u0 = (size_t)(head * 84 + b0);
  const float* O0 = pO + u0 * 8192;
  const float* L0 = pl + u0 * 64;

  __shared__ float ls[64];
  int t = threadIdx.x;
  if (t < 64) ls[t] = L0[t] + (nu == 2 ? L0[64 + t] : 0.f);
  __syncthreads();

  int q = t >> 2, dc = (t & 3) * 32;
  float inv = 1.f / ls[q];
  const float* a0 = O0 + q * 128 + dc;
  const float* a1 = a0 + 8192;
  u16 buf[32];
#pragma unroll
  for (int j = 0; j < 32; j += 4){
    float4 xv = *(const float4*)(a0 + j);
    if (nu == 2){
      float4 y = *(const float4*)(a1 + j);
      xv.x += y.x; xv.y += y.y; xv.z += y.z; xv.w += y.w;
    }
    buf[j]     = f2bf(xv.x * inv);
    buf[j + 1] = f2bf(xv.y * inv);
    buf[j + 2] = f2bf(xv.z * inv);
    buf[j + 3] = f2bf(xv.w * inv);
  }
  u16* op = ao + (size_t)(qblk * 64 + q) * DMODEL + head * HDIM + dc;
#pragma unroll
  for (int j = 0; j < 32; j += 8) *(bf16x8*)(op + j) = *(bf16x8*)(buf + j);
}

// ---------------- launch ----------------
extern "C" void kernel_launch(void* const* d_in, const int* in_sizes, int n_in,
                              void* d_out, int out_size, void* d_ws, size_t ws_size,
                              hipStream_t stream)
{
  const float* x    = (const float*)d_in[0];
  const float* Wq   = (const float*)d_in[1];
  const float* bq   = (const float*)d_in[2];
  const float* Wk   = (const float*)d_in[3];
  const float* bk   = (const float*)d_in[4];
  const float* Wv   = (const float*)d_in[5];
  const float* bv   = (const float*)d_in[6];
  const float* Wo   = (const float*)d_in[7];
  const float* bo   = (const float*)d_in[8];
  const float* gq   = (const float*)d_in[9];
  const float* gk   = (const float*)d_in[10];
  const float* fcos = (const float*)d_in[11];
  const float* fsin = (const float*)d_in[12];
  float* out = (float*)d_out;

  char* ws = (char*)d_ws;
  size_t off = 0;
  auto alloc = [&](size_t bytes){
    void* p = ws + off;
    off += (bytes + 255) & ~(size_t)255;
    return p;
  };
  const size_t SD = (size_t)SEQ * DMODEL;
  const size_t WW = (size_t)DMODEL * DMODEL;
  u16*   xb  = (u16*)  alloc(SD * 2);
  u16*   wqb = (u16*)  alloc(WW * 2);
  u16*   wkb = (u16*)  alloc(WW * 2);
  u16*   wvb = (u16*)  alloc(WW * 2);
  u16*   wob = (u16*)  alloc(WW * 2);
  float* qf  = (float*)alloc(SD * 4);
  float* kf  = (float*)alloc(SD * 4);
  u16*   rq  = (u16*)  alloc(SD * 2);
  u16*   rk  = (u16*)  alloc(SD * 2);
  u16*   vt  = (u16*)  alloc(SD * 2);
  u16*   ao  = (u16*)  alloc(SD * 2);
  float* pl  = (float*)alloc((size_t)1008 * 64 * 4);
  float* pO  = qf;   // aliases qf/kf region (dead after rmsrope)

  const int NX = (SEQ * DMODEL) / 4, NW = (DMODEL * DMODEL) / 4;
  cvt_all<<<(NX + 4 * NW) / 256, 256, 0, stream>>>(x, Wq, Wk, Wv, Wo, xb, wqb, wkb, wvb, wob);
  gemm_qkv256<<<216, 512, 0, stream>>>(xb, wqb, wkb, wvb, bq, bk, bv, qf, kf, vt);
  rmsrope_kernel<<<(SEQ * 2) / 4, 256, 0, stream>>>(qf, kf, gq, gk, fcos, fsin, rq, rk);
  attn_kernel<<<dim3(84, NHEAD), 256, 0, stream>>>(rq, rk, vt, pO, pl);
  attn_reduce<<<dim3(48, NHEAD), 256, 0, stream>>>(pO, pl, ao);
  gemm_o<<<dim3(SEQ / 128, DMODEL / 128), 256, 0, stream>>>(ao, wob, bo, out);
}

// Round 6
// 280.612 us; speedup vs baseline: 2.4120x; 1.0330x over previous
//
#include <hip/hip_runtime.h>
#include <stdint.h>

typedef unsigned short u16;
typedef __attribute__((ext_vector_type(8))) short bf16x8;
typedef __attribute__((ext_vector_type(4))) short bf16x4;
typedef __attribute__((ext_vector_type(4))) float f32x4;

constexpr int DMODEL = 1536;
constexpr int SEQ    = 3072;
constexpr int NHEAD  = 12;
constexpr int HDIM   = 128;

__device__ __forceinline__ u16 f2bf(float f){
  union { float f; unsigned u; } v; v.f = f;
  return (u16)((v.u + 0x7fffu + ((v.u >> 16) & 1u)) >> 16);
}

// ---------------- single fused f32 -> bf16 convert (x, Wq, Wk, Wv, Wo) ----------------
__global__ __launch_bounds__(256) void cvt_all(
    const float* __restrict__ x,  const float* __restrict__ wq,
    const float* __restrict__ wk, const float* __restrict__ wv, const float* __restrict__ wo,
    u16* __restrict__ xb, u16* __restrict__ wqb, u16* __restrict__ wkb,
    u16* __restrict__ wvb, u16* __restrict__ wob)
{
  const int NX = (SEQ * DMODEL) / 4;
  const int NW = (DMODEL * DMODEL) / 4;
  int i = blockIdx.x * 256 + threadIdx.x;
  const float* src; u16* dst; int off;
  if      (i < NX)          { src = x;  dst = xb;  off = i; }
  else if (i < NX + NW)     { src = wq; dst = wqb; off = i - NX; }
  else if (i < NX + 2 * NW) { src = wk; dst = wkb; off = i - NX - NW; }
  else if (i < NX + 3 * NW) { src = wv; dst = wvb; off = i - NX - 2 * NW; }
  else                      { src = wo; dst = wob; off = i - NX - 3 * NW; }
  float4 f = ((const float4*)src)[off];
  ushort4 o;
  o.x = f2bf(f.x); o.y = f2bf(f.y); o.z = f2bf(f.z); o.w = f2bf(f.w);
  ((ushort4*)dst)[off] = o;
}

__device__ __forceinline__ void gload16(const u16* g, u16* l){
  __builtin_amdgcn_global_load_lds((const __attribute__((address_space(1))) void*)g,
                                   (__attribute__((address_space(3))) void*)l, 16, 0, 0);
}

// ================= 8-phase 256x256 GEMM for QKV (BK=64, 8 waves, 128KiB LDS) =================
__global__ __launch_bounds__(512, 2) void gemm_qkv256(const u16* __restrict__ xb,
    const u16* __restrict__ wqb, const u16* __restrict__ wkb, const u16* __restrict__ wvb,
    const float* __restrict__ bq, const float* __restrict__ bk, const float* __restrict__ bv,
    float* __restrict__ qf, float* __restrict__ kf, u16* __restrict__ vt)
{
  __shared__ u16 lds[2][2][16384];   // [buf][A/B][256 rows x 64 k]

  const int tid  = threadIdx.x;
  const int lane = tid & 63;
  const int wid  = tid >> 6;
  const int wm   = wid >> 2;
  const int wn   = wid & 3;
  const int l15  = lane & 15, lg = lane >> 4;
  const int swz  = (l15 & 7) << 4;

  const int bid  = blockIdx.x;                 // 216 = 8 * 27
  const int sbid = (bid & 7) * 27 + (bid >> 3);
  const int mt   = sbid / 18, nt = sbid % 18;
  const int sel  = nt / 6, ntl = nt % 6;
  const u16* W = sel == 0 ? wqb : (sel == 1 ? wkb : wvb);
  const float* bias = sel == 0 ? bq : (sel == 1 ? bk : bv);
  const int m0 = mt * 256, n0 = ntl * 256;

  const char* Ag = (const char*)(xb + (size_t)m0 * DMODEL);
  const char* Bg = (const char*)(W  + (size_t)n0 * DMODEL);

  auto stage_op = [&](int buf, int op, const char* G, int kt){
#pragma unroll
    for (int c = 0; c < 4; c++){
      int ob  = c * 8192 + wid * 1024 + lane * 16;
      int row = ob >> 7, colb = ob & 127;
      gload16((const u16*)(G + (size_t)row * (DMODEL * 2) + (size_t)kt * 128
                             + (colb ^ ((row & 7) << 4))),
              (u16*)((char*)&lds[buf][op][0] + c * 8192 + wid * 1024));
    }
  };

  f32x4 acc[8][4];
#pragma unroll
  for (int i = 0; i < 8; i++)
#pragma unroll
    for (int j = 0; j < 4; j++){ f32x4 z = {0.f,0.f,0.f,0.f}; acc[i][j] = z; }

  const int NK = DMODEL / 64;

  stage_op(0, 0, Ag, 0);
  stage_op(0, 1, Bg, 0);
  asm volatile("s_waitcnt vmcnt(0)" ::: "memory");
  __builtin_amdgcn_sched_barrier(0);
  __builtin_amdgcn_s_barrier();
  __builtin_amdgcn_sched_barrier(0);

#pragma unroll 1
  for (int t = 0; t < NK; t++){
    const int b = t & 1;
    const char* Abase = (const char*)&lds[b][0][0];
    const char* Bbase = (const char*)&lds[b][1][0];
    bf16x8 bfr[4][2], afr[2][2];

#pragma unroll
    for (int ni = 0; ni < 4; ni++){
      int rb = wn * 64 + ni * 16 + l15;
#pragma unroll
      for (int ks = 0; ks < 2; ks++)
        bfr[ni][ks] = *(const bf16x8*)(Bbase + rb * 128 + ((ks * 64 + lg * 16) ^ swz));
    }
#pragma unroll
    for (int i = 0; i < 2; i++){
      int ra = wm * 128 + i * 16 + l15;
#pragma unroll
      for (int ks = 0; ks < 2; ks++)
        afr[i][ks] = *(const bf16x8*)(Abase + ra * 128 + ((ks * 64 + lg * 16) ^ swz));
    }
    if (t + 1 < NK) stage_op(b ^ 1, 0, Ag, t + 1);
    __builtin_amdgcn_sched_barrier(0);
    __builtin_amdgcn_s_barrier();
    __builtin_amdgcn_sched_barrier(0);
    __builtin_amdgcn_s_setprio(1);
#pragma unroll
    for (int i = 0; i < 2; i++)
#pragma unroll
      for (int ni = 0; ni < 4; ni++)
#pragma unroll
        for (int ks = 0; ks < 2; ks++)
          acc[i][ni] = __builtin_amdgcn_mfma_f32_16x16x32_bf16(afr[i][ks], bfr[ni][ks], acc[i][ni], 0, 0, 0);
    __builtin_amdgcn_s_setprio(0);
    __builtin_amdgcn_sched_barrier(0);
    __builtin_amdgcn_s_barrier();
    __builtin_amdgcn_sched_barrier(0);

#pragma unroll
    for (int qd = 1; qd < 4; qd++){
#pragma unroll
      for (int i = 0; i < 2; i++){
        int ra = wm * 128 + (qd * 2 + i) * 16 + l15;
#pragma unroll
        for (int ks = 0; ks < 2; ks++)
          afr[i][ks] = *(const bf16x8*)(Abase + ra * 128 + ((ks * 64 + lg * 16) ^ swz));
      }
      if (qd == 1 && t + 1 < NK) stage_op(b ^ 1, 1, Bg, t + 1);
      __builtin_amdgcn_sched_barrier(0);
      __builtin_amdgcn_s_barrier();
      __builtin_amdgcn_sched_barrier(0);
      __builtin_amdgcn_s_setprio(1);
#pragma unroll
      for (int i = 0; i < 2; i++)
#pragma unroll
        for (int ni = 0; ni < 4; ni++)
#pragma unroll
          for (int ks = 0; ks < 2; ks++)
            acc[qd * 2 + i][ni] = __builtin_amdgcn_mfma_f32_16x16x32_bf16(afr[i][ks], bfr[ni][ks], acc[qd * 2 + i][ni], 0, 0, 0);
      __builtin_amdgcn_s_setprio(0);
      if (qd == 3) asm volatile("s_waitcnt vmcnt(0)" ::: "memory");
      __builtin_amdgcn_sched_barrier(0);
      __builtin_amdgcn_s_barrier();
      __builtin_amdgcn_sched_barrier(0);
    }
  }

  if (sel != 2){
    float* C = sel == 0 ? qf : kf;
#pragma unroll
    for (int mi = 0; mi < 8; mi++){
      int row = m0 + wm * 128 + mi * 16 + lg * 4;
#pragma unroll
      for (int ni = 0; ni < 4; ni++){
        int col = n0 + wn * 64 + ni * 16 + l15;
        float bvv = bias[col];
#pragma unroll
        for (int r = 0; r < 4; r++)
          C[(size_t)(row + r) * DMODEL + col] = acc[mi][ni][r] + bvv;
      }
    }
  } else {
#pragma unroll
    for (int mi = 0; mi < 8; mi++){
      int gbase = m0 + wm * 128 + (mi >> 1) * 32 + lg * 8 + (mi & 1) * 4;
#pragma unroll
      for (int ni = 0; ni < 4; ni++){
        int d = n0 + wn * 64 + ni * 16 + l15;
        float bvv = bias[d];
        ushort4 o;
        o.x = f2bf(acc[mi][ni][0] + bvv);
        o.y = f2bf(acc[mi][ni][1] + bvv);
        o.z = f2bf(acc[mi][ni][2] + bvv);
        o.w = f2bf(acc[mi][ni][3] + bvv);
        *(ushort4*)(vt + (size_t)d * SEQ + gbase) = o;
      }
    }
  }
}

// ---------------- GEMM core (128^2, 2-phase) -- used by gemm_o ----------------
__device__ __forceinline__ void gemm_core(const u16* __restrict__ A, const u16* __restrict__ W,
    const float* __restrict__ bias, float* __restrict__ C, int m0, int n0,
    u16* As, u16* Bs)
{
  const int tid  = threadIdx.x;
  const int lane = tid & 63;
  const int wv   = tid >> 6;
  const int wm   = wv & 1, wn = wv >> 1;
  const int l15  = lane & 15, lg = lane >> 4;

  f32x4 acc[4][4];
#pragma unroll
  for (int i = 0; i < 4; i++)
#pragma unroll
    for (int j = 0; j < 4; j++){ f32x4 z = {0.f,0.f,0.f,0.f}; acc[i][j] = z; }

  const int r0 = wv * 16 + (lane >> 2);
  const int r1 = (wv + 4) * 16 + (lane >> 2);
  const int cc = (lane & 3) * 8;
  const u16* Ab = A + (size_t)m0 * DMODEL;
  const u16* Wb = W + (size_t)n0 * DMODEL;

  auto stageg = [&](int b, int k0){
    gload16(Ab + (size_t)r0 * DMODEL + k0 + cc, As + b * 4096 + wv * 512);
    gload16(Ab + (size_t)r1 * DMODEL + k0 + cc, As + b * 4096 + (wv + 4) * 512);
    gload16(Wb + (size_t)r0 * DMODEL + k0 + cc, Bs + b * 4096 + wv * 512);
    gload16(Wb + (size_t)r1 * DMODEL + k0 + cc, Bs + b * 4096 + (wv + 4) * 512);
  };

  stageg(0, 0);
  __syncthreads();

  for (int k0 = 0; k0 < DMODEL; k0 += 32){
    int b = (k0 >> 5) & 1;
    if (k0 + 32 < DMODEL) stageg(b ^ 1, k0 + 32);

    const u16* Ar = As + b * 4096;
    const u16* Br = Bs + b * 4096;
    bf16x8 af[4], bfr[4];
#pragma unroll
    for (int mi = 0; mi < 4; mi++)
      af[mi]  = *(const bf16x8*)(Ar + (wm * 64 + mi * 16 + l15) * 32 + lg * 8);
#pragma unroll
    for (int ni = 0; ni < 4; ni++)
      bfr[ni] = *(const bf16x8*)(Br + (wn * 64 + ni * 16 + l15) * 32 + lg * 8);
#pragma unroll
    for (int mi = 0; mi < 4; mi++)
#pragma unroll
      for (int ni = 0; ni < 4; ni++)
        acc[mi][ni] = __builtin_amdgcn_mfma_f32_16x16x32_bf16(af[mi], bfr[ni], acc[mi][ni], 0, 0, 0);
    __syncthreads();
  }

#pragma unroll
  for (int mi = 0; mi < 4; mi++){
    int row = m0 + wm * 64 + mi * 16 + (lg << 2);
#pragma unroll
    for (int ni = 0; ni < 4; ni++){
      int col = n0 + wn * 64 + ni * 16 + l15;
      float bvv = bias[col];
#pragma unroll
      for (int r = 0; r < 4; r++)
        C[(size_t)(row + r) * DMODEL + col] = acc[mi][ni][r] + bvv;
    }
  }
}

__global__ __launch_bounds__(256) void gemm_o(const u16* __restrict__ ab,
    const u16* __restrict__ wob, const float* __restrict__ bo, float* __restrict__ out)
{
  __shared__ u16 As[2 * 4096], Bs[2 * 4096];
  gemm_core(ab, wob, bo, out, blockIdx.x * 128, blockIdx.y * 128, As, Bs);
}

// ---------------- fused RMSNorm + RoPE: one wave per (token, q/k) row ----------------
__global__ __launch_bounds__(256) void rmsrope_kernel(
    const float* __restrict__ qin, const float* __restrict__ kin,
    const float* __restrict__ gq, const float* __restrict__ gk,
    const float* __restrict__ fcos, const float* __restrict__ fsin,
    u16* __restrict__ rq, u16* __restrict__ rk)
{
  int gw   = (blockIdx.x * 256 + threadIdx.x) >> 6;
  int lane = threadIdx.x & 63;
  int s    = gw >> 1;
  int pass = gw & 1;
  const float* in = pass ? kin : qin;
  const float* g  = pass ? gk  : gq;
  u16* outp       = pass ? rk  : rq;

  const float* row = in + (size_t)s * DMODEL + lane * 24;
  float v[24];
#pragma unroll
  for (int j = 0; j < 6; j++) *(float4*)(v + 4 * j) = ((const float4*)row)[j];

  float ss = 0.f;
#pragma unroll
  for (int j = 0; j < 24; j++) ss += v[j] * v[j];
#pragma unroll
  for (int m = 1; m < 64; m <<= 1) ss += __shfl_xor(ss, m);
  float scale = rsqrtf(ss * (1.0f / (float)DMODEL) + 1e-6f);

  float gv[24];
  const float* gp = g + lane * 24;
#pragma unroll
  for (int j = 0; j < 6; j++) *(float4*)(gv + 4 * j) = ((const float4*)gp)[j];

  int fi = s >> 8, hi2 = (s >> 4) & 15, wi = s & 15;
  u16 o[24];
#pragma unroll
  for (int jp = 0; jp < 12; jp++){
    int i  = lane * 12 + jp;
    int pi = i & 63;
    int idx = pi < 22 ? fi : (pi < 43 ? hi2 : wi);
    float cv = fcos[idx * 64 + pi];
    float sv = fsin[idx * 64 + pi];
    float xr = v[2 * jp]     * scale * gv[2 * jp];
    float xi = v[2 * jp + 1] * scale * gv[2 * jp + 1];
    o[2 * jp]     = f2bf(xr * cv - xi * sv);
    o[2 * jp + 1] = f2bf(xr * sv + xi * cv);
  }
  u16* op = outp + (size_t)s * DMODEL + lane * 24;
#pragma unroll
  for (int j = 0; j < 3; j++) *(bf16x8*)(op + 8 * j) = *(bf16x8*)(o + 8 * j);
}

// ---------------- attention v5: 32 q/wave (128 q/block), split-K, XCD-grouped heads ----------------
// 42 units/head x 12 heads = 504 = 8 XCDs x 63: unit u = (bid&7)*63 + bid>>3 keeps
// 63 consecutive units (1.5 heads' K/V, ~3MB) on one XCD's L2.
// Per 64-key tile per wave: 32 ds_read_b128 feed 64 MFMA (2x reuse via 2 q-groups).
__global__ __launch_bounds__(256, 2) void attn_kernel(const u16* __restrict__ rq,
    const u16* __restrict__ rk, const u16* __restrict__ vt,
    float* __restrict__ pO, float* __restrict__ pl)
{
  __shared__ u16 Ks[2][8192];
  __shared__ u16 Vs[2][8192];

  const int tid  = threadIdx.x;
  const int lane = tid & 63;
  const int wv   = tid >> 6;
  const int lin  = blockIdx.x;              // 0..503
  const int u    = (lin & 7) * 63 + (lin >> 3);
  const int head = u / 42;
  const int bid  = u % 42;
  int qb, blk, sub;
  if      (bid < 12){ qb = 3; blk = bid >> 1;        sub = bid & 1; }
  else if (bid < 24){ qb = 2; blk = (bid - 12) >> 1; sub = bid & 1; }
  else if (bid < 36){ qb = 1; blk = (bid - 24) >> 1; sub = bid & 1; }
  else              { qb = 0; blk = bid - 36;        sub = 0; }
  const int qblk = qb * 6 + blk;            // 0..23
  const int q0   = qblk * 128 + wv * 32;
  const int l15  = lane & 15, lg = lane >> 4;
  const int swz  = (l15 & 7) << 4;
  const float sc = 0.08838834764831845f;

  int r1s = 0, r1e = 0, r0e = 0;
  if      (qb == 0){ r0e = 768; }
  else if (qb == 1){ r0e = 1536; }
  else if (qb == 2){ r0e = 256; r1s = 768;  r1e = 2304; }
  else             { r0e = 256; r1s = 1536; r1e = 3072; }
  const int nt0 = r0e >> 6;
  const int nt  = nt0 + ((r1e - r1s) >> 6);
  const int hl  = (qb == 0) ? nt : (nt >> 1);
  const int ts  = sub * hl, te = ts + hl;

  const char* rkB = (const char*)rk;
  const char* vtB = (const char*)vt;
  auto k0_of = [&](int t){ return t < nt0 ? t * 64 : (r1s + (t - nt0) * 64); };

  auto stage = [&](int buf, int k0){
    char* Kd = (char*)Ks[buf];
    char* Vd = (char*)Vs[buf];
#pragma unroll
    for (int c = 0; c < 4; c++){
      int o = c * 4096 + wv * 1024 + lane * 16;
      int row = o >> 8, colb = o & 255;
      gload16((const u16*)(rkB + (size_t)(k0 + row) * (DMODEL * 2) + head * (HDIM * 2)
                               + (colb ^ ((row & 7) << 4))),
              (u16*)(Kd + c * 4096 + wv * 1024));
    }
#pragma unroll
    for (int c = 0; c < 4; c++){
      int o = c * 4096 + wv * 1024 + lane * 16;
      int row = o >> 7, colb = o & 127;
      gload16((const u16*)(vtB + (size_t)(head * HDIM + row) * (SEQ * 2) + (size_t)k0 * 2
                               + (colb ^ ((row & 7) << 4))),
              (u16*)(Vd + c * 4096 + wv * 1024));
    }
  };

  // Q fragments: 2 q-groups of 16 rows each
  bf16x8 qfr[2][4];
#pragma unroll
  for (int qg = 0; qg < 2; qg++){
    const u16* qbase = rq + (size_t)(q0 + qg * 16 + l15) * DMODEL + head * HDIM + lg * 8;
#pragma unroll
    for (int c = 0; c < 4; c++) qfr[qg][c] = *(const bf16x8*)(qbase + c * 32);
  }

  f32x4 oacc[2][8];
#pragma unroll
  for (int qg = 0; qg < 2; qg++)
#pragma unroll
    for (int i = 0; i < 8; i++){ f32x4 z = {0.f,0.f,0.f,0.f}; oacc[qg][i] = z; }
  float l_run[2] = {0.f, 0.f};

  stage(0, k0_of(ts));
  __syncthreads();

  for (int t = ts; t < te; t++){
    int buf = (t - ts) & 1;
    if (t + 1 < te) stage(buf ^ 1, k0_of(t + 1));

    const char* Kb = (const char*)Ks[buf];
    const char* Vb = (const char*)Vs[buf];
#pragma unroll
    for (int half = 0; half < 2; half++){
      const int kt = half * 32;
      const char* kr0 = Kb + (kt + l15) * 256;
      const char* kr1 = kr0 + 16 * 256;
      bf16x8 kf0[4], kf1[4];
#pragma unroll
      for (int c = 0; c < 4; c++){
        kf0[c] = *(const bf16x8*)(kr0 + ((lg * 16 + c * 64) ^ swz));
        kf1[c] = *(const bf16x8*)(kr1 + ((lg * 16 + c * 64) ^ swz));
      }
      f32x4 s0[2], s1[2];
#pragma unroll
      for (int qg = 0; qg < 2; qg++){ f32x4 z = {0.f,0.f,0.f,0.f}; s0[qg] = z; s1[qg] = z; }
      __builtin_amdgcn_s_setprio(1);
#pragma unroll
      for (int c = 0; c < 4; c++)
#pragma unroll
        for (int qg = 0; qg < 2; qg++){
          s0[qg] = __builtin_amdgcn_mfma_f32_16x16x32_bf16(kf0[c], qfr[qg][c], s0[qg], 0, 0, 0);
          s1[qg] = __builtin_amdgcn_mfma_f32_16x16x32_bf16(kf1[c], qfr[qg][c], s1[qg], 0, 0, 0);
        }
      __builtin_amdgcn_s_setprio(0);

      bf16x8 pf[2];
#pragma unroll
      for (int qg = 0; qg < 2; qg++){
        float lsum = 0.f;
#pragma unroll
        for (int r = 0; r < 4; r++){
          float e0 = __expf(fmaf(s0[qg][r], sc, -12.f));
          float e1 = __expf(fmaf(s1[qg][r], sc, -12.f));
          lsum += e0 + e1;
          pf[qg][r]     = (short)f2bf(e0);
          pf[qg][r + 4] = (short)f2bf(e1);
        }
        l_run[qg] += lsum;
      }

      __builtin_amdgcn_s_setprio(1);
#pragma unroll
      for (int ch = 0; ch < 8; ch++){
        bf16x8 vf8 = *(const bf16x8*)(Vb + (ch * 16 + l15) * 128 + ((half * 64 + lg * 16) ^ swz));
#pragma unroll
        for (int qg = 0; qg < 2; qg++)
          oacc[qg][ch] = __builtin_amdgcn_mfma_f32_16x16x32_bf16(pf[qg], vf8, oacc[qg][ch], 0, 0, 0);
      }
      __builtin_amdgcn_s_setprio(0);
    }
    __syncthreads();
  }

  const size_t punit = (size_t)(head * 42 + bid);
#pragma unroll
  for (int qg = 0; qg < 2; qg++){
    float lr = l_run[qg];
    lr += __shfl_xor(lr, 16);
    lr += __shfl_xor(lr, 32);
    if (lg == 0) pl[punit * 128 + wv * 32 + qg * 16 + l15] = lr;
  }

  float* po = pO + punit * 16384;
#pragma unroll
  for (int qg = 0; qg < 2; qg++)
#pragma unroll
    for (int ch = 0; ch < 8; ch++)
#pragma unroll
      for (int r = 0; r < 4; r++)
        po[(wv * 32 + qg * 16 + lg * 4 + r) * 128 + ch * 16 + l15] = oacc[qg][ch][r];
}

// ---------------- attn reduce: 128-q blocks ----------------
__global__ __launch_bounds__(256) void attn_reduce(const float* __restrict__ pO,
    const float* __restrict__ pl, u16* __restrict__ ao)
{
  const int qblk = blockIdx.x;   // 0..23
  const int head = blockIdx.y;
  const int qb = qblk / 6, blk = qblk % 6;
  int b0, nu;
  if      (qb == 0){ b0 = 36 + blk;     nu = 1; }
  else if (qb == 1){ b0 = 24 + 2 * blk; nu = 2; }
  else if (qb == 2){ b0 = 12 + 2 * blk; nu = 2; }
  else             { b0 = 2 * blk;      nu = 2; }
  const size_t u0 = (size_t)(head * 42 + b0);
  const float* O0 = pO + u0 * 16384;
  const float* L0 = pl + u0 * 128;

  __shared__ float ls[128];
  int t = threadIdx.x;
  if (t < 128) ls[t] = L0[t] + (nu == 2 ? L0[128 + t] : 0.f);
  __syncthreads();

  int q = t >> 1, dc = (t & 1) * 64;
  float inv = 1.f / ls[q];
  const float* a0 = O0 + q * 128 + dc;
  const float* a1 = a0 + 16384;
  u16 buf[64];
#pragma unroll
  for (int j = 0; j < 64; j += 4){
    float4 xv = *(const float4*)(a0 + j);
    if (nu == 2){
      float4 y = *(const float4*)(a1 + j);
      xv.x += y.x; xv.y += y.y; xv.z += y.z; xv.w += y.w;
    }
    buf[j]     = f2bf(xv.x * inv);
    buf[j + 1] = f2bf(xv.y * inv);
    buf[j + 2] = f2bf(xv.z * inv);
    buf[j + 3] = f2bf(xv.w * inv);
  }
  u16* op = ao + (size_t)(qblk * 128 + q) * DMODEL + head * HDIM + dc;
#pragma unroll
  for (int j = 0; j < 64; j += 8) *(bf16x8*)(op + j) = *(bf16x8*)(buf + j);
}

// ---------------- launch ----------------
extern "C" void kernel_launch(void* const* d_in, const int* in_sizes, int n_in,
                              void* d_out, int out_size, void* d_ws, size_t ws_size,
                              hipStream_t stream)
{
  const float* x    = (const float*)d_in[0];
  const float* Wq   = (const float*)d_in[1];
  const float* bq   = (const float*)d_in[2];
  const float* Wk   = (const float*)d_in[3];
  const float* bk   = (const float*)d_in[4];
  const float* Wv   = (const float*)d_in[5];
  const float* bv   = (const float*)d_in[6];
  const float* Wo   = (const float*)d_in[7];
  const float* bo   = (const float*)d_in[8];
  const float* gq   = (const float*)d_in[9];
  const float* gk   = (const float*)d_in[10];
  const float* fcos = (const float*)d_in[11];
  const float* fsin = (const float*)d_in[12];
  float* out = (float*)d_out;

  char* ws = (char*)d_ws;
  size_t off = 0;
  auto alloc = [&](size_t bytes){
    void* p = ws + off;
    off += (bytes + 255) & ~(size_t)255;
    return p;
  };
  const size_t SD = (size_t)SEQ * DMODEL;
  const size_t WW = (size_t)DMODEL * DMODEL;
  u16*   xb  = (u16*)  alloc(SD * 2);
  u16*   wqb = (u16*)  alloc(WW * 2);
  u16*   wkb = (u16*)  alloc(WW * 2);
  u16*   wvb = (u16*)  alloc(WW * 2);
  u16*   wob = (u16*)  alloc(WW * 2);
  float* qf  = (float*)alloc(SD * 4);
  float* kf  = (float*)alloc(SD * 4);
  u16*   rq  = (u16*)  alloc(SD * 2);
  u16*   rk  = (u16*)  alloc(SD * 2);
  u16*   vt  = (u16*)  alloc(SD * 2);
  u16*   ao  = (u16*)  alloc(SD * 2);
  float* pl  = (float*)alloc((size_t)504 * 128 * 4);
  float* pO  = qf;   // aliases qf/kf region (dead after rmsrope): 504*64KB = 33MB < 37.7MB

  const int NX = (SEQ * DMODEL) / 4, NW = (DMODEL * DMODEL) / 4;
  cvt_all<<<(NX + 4 * NW) / 256, 256, 0, stream>>>(x, Wq, Wk, Wv, Wo, xb, wqb, wkb, wvb, wob);
  gemm_qkv256<<<216, 512, 0, stream>>>(xb, wqb, wkb, wvb, bq, bk, bv, qf, kf, vt);
  rmsrope_kernel<<<(SEQ * 2) / 4, 256, 0, stream>>>(qf, kf, gq, gk, fcos, fsin, rq, rk);
  attn_kernel<<<504, 256, 0, stream>>>(rq, rk, vt, pO, pl);
  attn_reduce<<<dim3(24, NHEAD), 256, 0, stream>>>(pO, pl, ao);
  gemm_o<<<dim3(SEQ / 128, DMODEL / 128), 256, 0, stream>>>(ao, wob, bo, out);
}